// Round 11
// baseline (140.758 us; speedup 1.0000x reference)
//
#include <hip/hip_runtime.h>

// Causal self-attention: B=1, T=4096, C=768, H=12, hd=64
// f32 in/out, bf16 MFMA compute internally. Flash-decoding s-split.
// R11: attn frozen at R10 (71us). Non-attn trims: fused prep kernel (1 launch
// instead of 3), GEMM bijective XCD swizzle (per-XCD A-chunk L2-resident),
// GEMM __launch_bounds__(256,4) (VGPR cap 128, no spill expected).

typedef short bf16x8 __attribute__((ext_vector_type(8)));
typedef float f32x4 __attribute__((ext_vector_type(4)));

#define T_SEQ 4096
#define C_DIM 768
#define NH 12
#define HD 64

__device__ __forceinline__ unsigned short f2bf(float f) {
  union { float f; unsigned u; } v; v.f = f;
  unsigned r = v.u + 0x7FFFu + ((v.u >> 16) & 1u);
  return (unsigned short)(r >> 16);
}
__device__ __forceinline__ float bf2f(unsigned short u) {
  union { unsigned u; float f; } v; v.u = ((unsigned)u) << 16;
  return v.f;
}
__device__ __forceinline__ unsigned cvtpk(float a, float b) {
  unsigned r;
  asm("v_cvt_pk_bf16_f32 %0, %1, %2" : "=v"(r) : "v"(a), "v"(b));
  return r;
}
#define E2(x) __builtin_amdgcn_exp2f(x)

#define GLD16(g, l) __builtin_amdgcn_global_load_lds( \
    (const __attribute__((address_space(1))) void*)(g), \
    (__attribute__((address_space(3))) void*)(l), 16, 0, 0)

// ---------------- fused prep: f32->bf16 conv + 2 weight transposes ----------------
__device__ __forceinline__ void tr_body(const float* __restrict__ in,
                                        unsigned short* __restrict__ out,
                                        int R, int Cc, int bx, int by,
                                        float (*tile)[33]) {
  int tx = threadIdx.x & 31, ty = threadIdx.x >> 5;
#pragma unroll
  for (int i = 0; i < 32; i += 8)
    tile[ty + i][tx] = in[(size_t)(by * 32 + ty + i) * Cc + bx * 32 + tx];
  __syncthreads();
#pragma unroll
  for (int i = 0; i < 32; i += 8)
    out[(size_t)(bx * 32 + ty + i) * R + by * 32 + tx] = f2bf(tile[tx][ty + i]);
}

__global__ void prep(const float* __restrict__ x, unsigned short* __restrict__ Xb,
                     const float* __restrict__ w_attn, unsigned short* __restrict__ WaT,
                     const float* __restrict__ w_proj, unsigned short* __restrict__ WpT) {
  __shared__ float tile[32][33];
  const int bid = blockIdx.x;
  if (bid < 3072) {                       // conv x: 4096x768 f32 -> bf16
    int i = (bid * 256 + threadIdx.x) * 4;
    float4 v = *reinterpret_cast<const float4*>(x + i);
    ushort4 o;
    o.x = f2bf(v.x); o.y = f2bf(v.y); o.z = f2bf(v.z); o.w = f2bf(v.w);
    *reinterpret_cast<ushort4*>(Xb + i) = o;
  } else if (bid < 3072 + 1728) {         // w_attn^T: 768x2304 -> [2304][768]
    int b = bid - 3072;
    tr_body(w_attn, WaT, 768, 2304, b % 72, b / 72, tile);
  } else {                                // w_proj^T: 768x768 -> [768][768]
    int b = bid - 4800;
    tr_body(w_proj, WpT, 768, 768, b % 24, b / 24, tile);
  }
}

// ---------------- BT-GEMM: A[M][K] bf16 @ Bt[N][K] bf16 ----------------
// Tile 128x64, 1-D grid with bijective XCD swizzle: each XCD owns a
// contiguous 4-bm x all-bn chunk -> per-XCD A working set ~0.8MB (L2-fit).
template <int MODE>
__global__ __launch_bounds__(256, 4)
void gemm_bt(const unsigned short* __restrict__ A,
             const unsigned short* __restrict__ Bt,
             void* __restrict__ out0,
             unsigned short* __restrict__ Kout,
             unsigned short* __restrict__ Vt,
             int M, int N, int K) {
  __shared__ __align__(16) unsigned short As[128 * 64];
  __shared__ __align__(16) unsigned short Bs[64 * 64];
  const int nbn = N / 64;
  const int nwg = (M / 128) * nbn;
  const int cpx = nwg >> 3;               // nwg % 8 == 0 (1152, 384)
  const int swz = ((int)blockIdx.x & 7) * cpx + ((int)blockIdx.x >> 3);
  const int bm = swz / nbn, bn = swz % nbn;
  const int tid = threadIdx.x;
  const int wid = tid >> 6, lane = tid & 63;
  const int wr = wid >> 1, wc = wid & 1;
  const int lr = lane & 15;
  const int lk8 = (lane >> 4) * 8;
  const int rsub = lane >> 3, csub = (lane & 7) * 8;

  f32x4 acc[4][2] = {};

  const int nk = K / 64;
  for (int kt = 0; kt < nk; ++kt) {
    __syncthreads();
    {
      const unsigned short* gA = A + (size_t)(bm * 128) * K + kt * 64;
      const unsigned short* gB = Bt + (size_t)(bn * 64) * K + kt * 64;
#pragma unroll
      for (int c = 0; c < 4; ++c) {
        int seg = wid * 4 + c;            // A: 16 segs of 1KB
        int row = seg * 8 + rsub;
        GLD16(gA + (size_t)row * K + csub, (char*)As + seg * 1024);
      }
#pragma unroll
      for (int c = 0; c < 2; ++c) {
        int seg = wid * 2 + c;            // B: 8 segs of 1KB
        int row = seg * 8 + rsub;
        GLD16(gB + (size_t)row * K + csub, (char*)Bs + seg * 1024);
      }
    }
    __syncthreads();
#pragma unroll
    for (int kk = 0; kk < 2; ++kk) {
      bf16x8 a[4], b[2];
      int lk = kk * 32 + lk8;
#pragma unroll
      for (int m = 0; m < 4; ++m)
        a[m] = *reinterpret_cast<const bf16x8*>(&As[(wr * 64 + m * 16 + lr) * 64 + lk]);
#pragma unroll
      for (int n = 0; n < 2; ++n)
        b[n] = *reinterpret_cast<const bf16x8*>(&Bs[(wc * 32 + n * 16 + lr) * 64 + lk]);
#pragma unroll
      for (int m = 0; m < 4; ++m)
#pragma unroll
        for (int n = 0; n < 2; ++n)
          acc[m][n] = __builtin_amdgcn_mfma_f32_16x16x32_bf16(a[m], b[n], acc[m][n], 0, 0, 0);
    }
  }

  const int row0 = bm * 128 + wr * 64;
  const int col0 = bn * 64 + wc * 32;
#pragma unroll
  for (int m = 0; m < 4; ++m)
#pragma unroll
    for (int n = 0; n < 2; ++n)
#pragma unroll
      for (int j = 0; j < 4; ++j) {
        int r = row0 + m * 16 + (lane >> 4) * 4 + j;
        int c = col0 + n * 16 + (lane & 15);
        float v = acc[m][n][j];
        if (MODE == 0) {
          if (c < 768)  // Q pre-scaled by (1/8)*log2(e) for exp2-domain softmax
            ((unsigned short*)out0)[(size_t)r * 768 + c] = f2bf(v * 0.180336884f);
          else if (c < 1536)
            Kout[(size_t)r * 768 + (c - 768)] = f2bf(v);
          else
            Vt[(size_t)(c - 1536) * M + r] = f2bf(v);
        } else {
          ((float*)out0)[(size_t)r * N + c] = v;
        }
      }
}

// ---------------- attention helpers ----------------
__device__ __forceinline__ void stage_kv(const unsigned short* __restrict__ Kb,
                                         const unsigned short* __restrict__ Vt,
                                         unsigned short* Kbuf, unsigned short* Vbuf,
                                         int h, int st, int wid, int lane) {
  const int cg = lane & 7, rsub = (lane >> 3) & 7;
  const unsigned short* gK = Kb + (size_t)(st * 64) * C_DIM + h * 64;
  const unsigned short* gV = Vt + (size_t)(h * 64) * T_SEQ + st * 64;
#pragma unroll
  for (int c = 0; c < 2; ++c) {
    int seg = wid * 2 + c;
    int row = seg * 8 + rsub;
    GLD16(gK + (size_t)row * C_DIM + (cg ^ rsub) * 8, (char*)Kbuf + seg * 1024);
    GLD16(gV + (size_t)row * T_SEQ + (cg ^ rsub) * 8, (char*)Vbuf + seg * 1024);
  }
}

// partial set id: per head 72 sets (qb>=8 only). offset within head:
__device__ __forceinline__ int part_off(int qb) {
  return (qb < 16) ? (qb - 8) * 2 : (qb < 24) ? 16 + (qb - 16) * 3 : 40 + (qb - 24) * 4;
}
__device__ __forceinline__ unsigned short* part_ptr(char* pA, char* pB, int set) {
  return (set < 768) ? (unsigned short*)(pA + (size_t)set * 16384)
                     : (unsigned short*)(pB + (size_t)(set - 768) * 16384);
}

// ---------------- flash attention (causal, swapped QK^T, s-chunked) ----------------
// grid = (NH, 80): x = head (fastest dispatch dim) so the qb-descending chunk
// slots in y dispatch longest-first across ALL heads (LPT makespan).
// global_load_lds staging (reg-staging spills: R4/R5); min-waves 3.
__global__ __launch_bounds__(256, 3)
void attn_fwd(const unsigned short* __restrict__ Qb,
              const unsigned short* __restrict__ Kb,
              const unsigned short* __restrict__ Vt,
              unsigned short* __restrict__ Y,
              char* __restrict__ partA, char* __restrict__ partB,
              float* __restrict__ ml) {
  __shared__ __align__(16) unsigned short Ks[2][64 * 64];
  __shared__ __align__(16) unsigned short Vs[2][64 * 64];  // [d][s]
  __shared__ __align__(16) unsigned short Ps[4][32 * 64];

  const int h = blockIdx.x;
  int qb = 0, ck = 0;
  {
    int idx = blockIdx.y;
    for (int q = 31; q >= 0; --q) {
      int nc = q / 8 + 1;
      if (idx < nc) { qb = q; ck = idx; break; }
      idx -= nc;
    }
  }
  const int nch = qb / 8 + 1;
  const int q0 = qb * 128;
  const int nst_total = q0 / 64 + 2;
  const int st0 = ck * 16;
  const int st1 = (st0 + 16 < nst_total) ? st0 + 16 : nst_total;

  const int tid = threadIdx.x;
  const int wid = tid >> 6, lane = tid & 63;
  const int l15 = lane & 15, g = lane >> 4;
  const int sw = l15 & 7;
  const int qw = q0 + wid * 32;

  bf16x8 qf[2][2];
#pragma unroll
  for (int m = 0; m < 2; ++m)
#pragma unroll
    for (int kk = 0; kk < 2; ++kk)
      qf[m][kk] = *reinterpret_cast<const bf16x8*>(
          &Qb[(size_t)(qw + m * 16 + l15) * C_DIM + h * 64 + kk * 32 + g * 8]);

  f32x4 o[2][4] = {};  // O^T fragments: row=d, col=q
  float mrow[2] = {-1e30f, -1e30f};
  float lsum[2] = {0.f, 0.f};

  stage_kv(Kb, Vt, Ks[0], Vs[0], h, st0, wid, lane);
  int cur = 0;

  for (int st = st0; st < st1; ++st) {
    if (st + 1 < st1) {
      stage_kv(Kb, Vt, Ks[cur ^ 1], Vs[cur ^ 1], h, st + 1, wid, lane);
      asm volatile("s_waitcnt vmcnt(4)" ::: "memory");  // cur tile's 4 loads done
    } else {
      asm volatile("s_waitcnt vmcnt(0)" ::: "memory");
    }
    __builtin_amdgcn_s_barrier();

    const bool active = (st * 64) <= (qw + 31);
    if (active) {
      const unsigned short* K_ = Ks[cur];
      const unsigned short* V_ = Vs[cur];

      // S^T = K @ Q^T  (S in log2 domain: Q pre-scaled by 0.125*log2e)
      f32x4 sT[2][4] = {};
      __builtin_amdgcn_s_setprio(1);
#pragma unroll
      for (int kk = 0; kk < 2; ++kk) {
        bf16x8 kf[4];
#pragma unroll
        for (int n = 0; n < 4; ++n)
          kf[n] = *reinterpret_cast<const bf16x8*>(
              &K_[(n * 16 + l15) * 64 + (((kk * 4 + g) ^ sw) * 8)]);
#pragma unroll
        for (int m = 0; m < 2; ++m)
#pragma unroll
          for (int n = 0; n < 4; ++n)
            sT[m][n] = __builtin_amdgcn_mfma_f32_16x16x32_bf16(kf[n], qf[m][kk], sT[m][n], 0, 0, 0);
      }
      __builtin_amdgcn_s_setprio(0);

      unsigned short* Pw = Ps[wid];
#pragma unroll
      for (int m = 0; m < 2; ++m) {
        float vmax = -1e30f;
        if (st * 64 + 63 <= qw + m * 16) {
          // fully unmasked tile for this row-block (wave-uniform branch)
#pragma unroll
          for (int n = 0; n < 4; ++n)
#pragma unroll
            for (int jj = 0; jj < 4; ++jj) vmax = fmaxf(vmax, sT[m][n][jj]);
        } else {
          const int bound = (qw + m * 16 + l15) - st * 64;
#pragma unroll
          for (int n = 0; n < 4; ++n)
#pragma unroll
            for (int jj = 0; jj < 4; ++jj) {
              int sl = n * 16 + g * 4 + jj;
              float v = sT[m][n][jj];
              v = (sl <= bound) ? v : -1e30f;
              sT[m][n][jj] = v;
              vmax = fmaxf(vmax, v);
            }
        }
        vmax = fmaxf(vmax, __shfl_xor(vmax, 16, 64));
        vmax = fmaxf(vmax, __shfl_xor(vmax, 32, 64));
        // defer-rescale (T13): keep old max while growth <= 8 (P bounded by 2^8)
        const bool defer = (__all(vmax <= mrow[m] + 8.0f) != 0);
        const float mnew = defer ? mrow[m] : fmaxf(mrow[m], vmax);
        float ps = 0.f;
#pragma unroll
        for (int n = 0; n < 4; ++n)
#pragma unroll
          for (int jj = 0; jj < 4; ++jj) {
            float p = E2(sT[m][n][jj] - mnew);
            sT[m][n][jj] = p;
            ps += p;
          }
        ps += __shfl_xor(ps, 16, 64);
        ps += __shfl_xor(ps, 32, 64);
        if (defer) {
          lsum[m] += ps;
        } else {
          float alpha = E2(mrow[m] - mnew);
          lsum[m] = lsum[m] * alpha + ps;
          mrow[m] = mnew;
#pragma unroll
          for (int n2 = 0; n2 < 4; ++n2) o[m][n2] *= alpha;
        }
#pragma unroll
        for (int n = 0; n < 4; ++n) {
          uint2 pw;
          pw.x = cvtpk(sT[m][n][0], sT[m][n][1]);
          pw.y = cvtpk(sT[m][n][2], sT[m][n][3]);
          *reinterpret_cast<uint2*>(
              &Pw[(m * 16 + l15) * 64 + (((n * 2 + (g >> 1)) ^ sw) * 8) + (g & 1) * 4]) = pw;
        }
      }
      asm volatile("s_waitcnt lgkmcnt(0)" ::: "memory");

      // O^T += V^T @ P^T
      __builtin_amdgcn_s_setprio(1);
#pragma unroll
      for (int ks = 0; ks < 2; ++ks) {
        bf16x8 vf[4], pf[2];
#pragma unroll
        for (int n2 = 0; n2 < 4; ++n2)
          vf[n2] = *reinterpret_cast<const bf16x8*>(
              &V_[(n2 * 16 + l15) * 64 + (((ks * 4 + g) ^ sw) * 8)]);
#pragma unroll
        for (int m = 0; m < 2; ++m)
          pf[m] = *reinterpret_cast<const bf16x8*>(
              &Pw[(m * 16 + l15) * 64 + (((ks * 4 + g) ^ sw) * 8)]);
#pragma unroll
        for (int m = 0; m < 2; ++m)
#pragma unroll
          for (int n2 = 0; n2 < 4; ++n2)
            o[m][n2] = __builtin_amdgcn_mfma_f32_16x16x32_bf16(vf[n2], pf[m], o[m][n2], 0, 0, 0);
      }
      __builtin_amdgcn_s_setprio(0);
    }
    asm volatile("" ::: "memory");
    __builtin_amdgcn_s_barrier();
    cur ^= 1;
  }

  if (nch == 1) {
#pragma unroll
    for (int m = 0; m < 2; ++m) {
      float inv = 1.0f / lsum[m];
      int qg = qw + m * 16 + l15;
#pragma unroll
      for (int n2 = 0; n2 < 4; ++n2) {
        uint2 yk;
        yk.x = cvtpk(o[m][n2][0] * inv, o[m][n2][1] * inv);
        yk.y = cvtpk(o[m][n2][2] * inv, o[m][n2][3] * inv);
        *reinterpret_cast<uint2*>(&Y[(size_t)qg * C_DIM + h * 64 + n2 * 16 + g * 4]) = yk;
      }
    }
  } else {
    const int set = h * 72 + part_off(qb) + ck;
    unsigned short* po = part_ptr(partA, partB, set);
#pragma unroll
    for (int m = 0; m < 2; ++m) {
      int qL = wid * 32 + m * 16 + l15;
#pragma unroll
      for (int n2 = 0; n2 < 4; ++n2) {
        uint2 pk;
        pk.x = cvtpk(o[m][n2][0], o[m][n2][1]);
        pk.y = cvtpk(o[m][n2][2], o[m][n2][3]);
        *reinterpret_cast<uint2*>(&po[qL * 64 + n2 * 16 + g * 4]) = pk;
      }
      if (g == 0) {
        ml[(size_t)set * 256 + qL * 2] = mrow[m];
        ml[(size_t)set * 256 + qL * 2 + 1] = lsum[m];
      }
    }
  }
}

// ---------------- combine partials (exp2 domain) ----------------
__global__ __launch_bounds__(256)
void attn_combine(char* __restrict__ partA, char* __restrict__ partB,
                  const float* __restrict__ ml, unsigned short* __restrict__ Y) {
  const int qb = 8 + blockIdx.x;
  const int h = blockIdx.y;
  const int nch = qb / 8 + 1;
  const int set0 = h * 72 + part_off(qb);
  const int t = threadIdx.x;
  const int r = t >> 1, dh = (t & 1) * 32;

  float mi[4], li[4];
  float M = -1e30f;
  for (int i = 0; i < nch; ++i) {
    mi[i] = ml[(size_t)(set0 + i) * 256 + r * 2];
    li[i] = ml[(size_t)(set0 + i) * 256 + r * 2 + 1];
    M = fmaxf(M, mi[i]);
  }
  float L = 0.f;
  float O[32];
#pragma unroll
  for (int d = 0; d < 32; ++d) O[d] = 0.f;
  for (int i = 0; i < nch; ++i) {
    float w = E2(mi[i] - M);
    L += li[i] * w;
    const unsigned short* po = part_ptr(partA, partB, set0 + i) + r * 64 + dh;
#pragma unroll
    for (int d4 = 0; d4 < 32; d4 += 4) {
      ushort4 v = *reinterpret_cast<const ushort4*>(po + d4);
      O[d4 + 0] += bf2f(v.x) * w;
      O[d4 + 1] += bf2f(v.y) * w;
      O[d4 + 2] += bf2f(v.z) * w;
      O[d4 + 3] += bf2f(v.w) * w;
    }
  }
  float inv = 1.0f / L;
  unsigned short* yp = Y + (size_t)(qb * 128 + r) * C_DIM + h * 64 + dh;
#pragma unroll
  for (int d4 = 0; d4 < 32; d4 += 4) {
    uint2 yk;
    yk.x = cvtpk(O[d4 + 0] * inv, O[d4 + 1] * inv);
    yk.y = cvtpk(O[d4 + 2] * inv, O[d4 + 3] * inv);
    *reinterpret_cast<uint2*>(yp + d4) = yk;
  }
}

// ---------------- launcher ----------------
extern "C" void kernel_launch(void* const* d_in, const int* in_sizes, int n_in,
                              void* d_out, int out_size, void* d_ws, size_t ws_size,
                              hipStream_t stream) {
  const float* x = (const float*)d_in[0];       // [4096][768]
  const float* w_attn = (const float*)d_in[1];  // [768][2304]
  const float* w_proj = (const float*)d_in[2];  // [768][768]
  float* out = (float*)d_out;                   // [4096][768] f32

  char* ws = (char*)d_ws;
  unsigned short* Xb   = (unsigned short*)(ws + 0);          // 6291456 B (dead after QKV -> part spill B)
  unsigned short* WaT  = (unsigned short*)(ws + 6291456);    // 3538944 B (dead after QKV -> ml)
  unsigned short* WpT  = (unsigned short*)(ws + 9830400);    // 1179648 B [768][768]
  unsigned short* Qb   = (unsigned short*)(ws + 11010048);   // 6291456 B [T][768]
  unsigned short* Kb   = (unsigned short*)(ws + 17301504);   // 6291456 B [T][768]
  unsigned short* Vt   = (unsigned short*)(ws + 23592960);   // 6291456 B [768][T]
  unsigned short* Yb   = (unsigned short*)(ws + 29884416);   // 6291456 B [T][768]

  char* partA = (char*)d_out;            // free during attention; overwritten by proj GEMM
  char* partB = (char*)ws;               // Xb region, dead after QKV GEMM
  float* mlp  = (float*)(ws + 6291456);  // WaT region, dead after QKV GEMM

  prep<<<5376, 256, 0, stream>>>(x, Xb, w_attn, WaT, w_proj, WpT);

  gemm_bt<0><<<(T_SEQ / 128) * (2304 / 64), 256, 0, stream>>>(
      Xb, WaT, (void*)Qb, Kb, Vt, T_SEQ, 2304, C_DIM);

  attn_fwd<<<dim3(NH, 80), 256, 0, stream>>>(Qb, Kb, Vt, Yb, partA, partB, mlp);
  attn_combine<<<dim3(24, NH), 256, 0, stream>>>(partA, partB, mlp, Yb);

  gemm_bt<1><<<(T_SEQ / 128) * (C_DIM / 64), 256, 0, stream>>>(
      Yb, WpT, (void*)out, nullptr, nullptr, T_SEQ, C_DIM, C_DIM);
}

// Round 12
// 138.050 us; speedup vs baseline: 1.0196x; 1.0196x over previous
//
#include <hip/hip_runtime.h>

// Causal self-attention: B=1, T=4096, C=768, H=12, hd=64
// f32 in/out, bf16 MFMA compute internally. Flash-decoding s-split.
// R12: attn chunk 16->12 tiles (960->1224 blocks; drain-tail/occupancy was the
// limiter, not LDS: R9 evidence) + tree-shaped vmax/psum reductions.
// GEMMs/prep frozen at R11.

typedef short bf16x8 __attribute__((ext_vector_type(8)));
typedef float f32x4 __attribute__((ext_vector_type(4)));

#define T_SEQ 4096
#define C_DIM 768
#define NH 12
#define HD 64

__device__ __forceinline__ unsigned short f2bf(float f) {
  union { float f; unsigned u; } v; v.f = f;
  unsigned r = v.u + 0x7FFFu + ((v.u >> 16) & 1u);
  return (unsigned short)(r >> 16);
}
__device__ __forceinline__ float bf2f(unsigned short u) {
  union { unsigned u; float f; } v; v.u = ((unsigned)u) << 16;
  return v.f;
}
__device__ __forceinline__ unsigned cvtpk(float a, float b) {
  unsigned r;
  asm("v_cvt_pk_bf16_f32 %0, %1, %2" : "=v"(r) : "v"(a), "v"(b));
  return r;
}
#define E2(x) __builtin_amdgcn_exp2f(x)

#define GLD16(g, l) __builtin_amdgcn_global_load_lds( \
    (const __attribute__((address_space(1))) void*)(g), \
    (__attribute__((address_space(3))) void*)(l), 16, 0, 0)

// ---------------- fused prep: f32->bf16 conv + 2 weight transposes ----------------
__device__ __forceinline__ void tr_body(const float* __restrict__ in,
                                        unsigned short* __restrict__ out,
                                        int R, int Cc, int bx, int by,
                                        float (*tile)[33]) {
  int tx = threadIdx.x & 31, ty = threadIdx.x >> 5;
#pragma unroll
  for (int i = 0; i < 32; i += 8)
    tile[ty + i][tx] = in[(size_t)(by * 32 + ty + i) * Cc + bx * 32 + tx];
  __syncthreads();
#pragma unroll
  for (int i = 0; i < 32; i += 8)
    out[(size_t)(bx * 32 + ty + i) * R + by * 32 + tx] = f2bf(tile[tx][ty + i]);
}

__global__ void prep(const float* __restrict__ x, unsigned short* __restrict__ Xb,
                     const float* __restrict__ w_attn, unsigned short* __restrict__ WaT,
                     const float* __restrict__ w_proj, unsigned short* __restrict__ WpT) {
  __shared__ float tile[32][33];
  const int bid = blockIdx.x;
  if (bid < 3072) {                       // conv x: 4096x768 f32 -> bf16
    int i = (bid * 256 + threadIdx.x) * 4;
    float4 v = *reinterpret_cast<const float4*>(x + i);
    ushort4 o;
    o.x = f2bf(v.x); o.y = f2bf(v.y); o.z = f2bf(v.z); o.w = f2bf(v.w);
    *reinterpret_cast<ushort4*>(Xb + i) = o;
  } else if (bid < 3072 + 1728) {         // w_attn^T: 768x2304 -> [2304][768]
    int b = bid - 3072;
    tr_body(w_attn, WaT, 768, 2304, b % 72, b / 72, tile);
  } else {                                // w_proj^T: 768x768 -> [768][768]
    int b = bid - 4800;
    tr_body(w_proj, WpT, 768, 768, b % 24, b / 24, tile);
  }
}

// ---------------- BT-GEMM: A[M][K] bf16 @ Bt[N][K] bf16 ----------------
// Tile 128x64, 1-D grid with bijective XCD swizzle.
template <int MODE>
__global__ __launch_bounds__(256, 4)
void gemm_bt(const unsigned short* __restrict__ A,
             const unsigned short* __restrict__ Bt,
             void* __restrict__ out0,
             unsigned short* __restrict__ Kout,
             unsigned short* __restrict__ Vt,
             int M, int N, int K) {
  __shared__ __align__(16) unsigned short As[128 * 64];
  __shared__ __align__(16) unsigned short Bs[64 * 64];
  const int nbn = N / 64;
  const int nwg = (M / 128) * nbn;
  const int cpx = nwg >> 3;               // nwg % 8 == 0 (1152, 384)
  const int swz = ((int)blockIdx.x & 7) * cpx + ((int)blockIdx.x >> 3);
  const int bm = swz / nbn, bn = swz % nbn;
  const int tid = threadIdx.x;
  const int wid = tid >> 6, lane = tid & 63;
  const int wr = wid >> 1, wc = wid & 1;
  const int lr = lane & 15;
  const int lk8 = (lane >> 4) * 8;
  const int rsub = lane >> 3, csub = (lane & 7) * 8;

  f32x4 acc[4][2] = {};

  const int nk = K / 64;
  for (int kt = 0; kt < nk; ++kt) {
    __syncthreads();
    {
      const unsigned short* gA = A + (size_t)(bm * 128) * K + kt * 64;
      const unsigned short* gB = Bt + (size_t)(bn * 64) * K + kt * 64;
#pragma unroll
      for (int c = 0; c < 4; ++c) {
        int seg = wid * 4 + c;            // A: 16 segs of 1KB
        int row = seg * 8 + rsub;
        GLD16(gA + (size_t)row * K + csub, (char*)As + seg * 1024);
      }
#pragma unroll
      for (int c = 0; c < 2; ++c) {
        int seg = wid * 2 + c;            // B: 8 segs of 1KB
        int row = seg * 8 + rsub;
        GLD16(gB + (size_t)row * K + csub, (char*)Bs + seg * 1024);
      }
    }
    __syncthreads();
#pragma unroll
    for (int kk = 0; kk < 2; ++kk) {
      bf16x8 a[4], b[2];
      int lk = kk * 32 + lk8;
#pragma unroll
      for (int m = 0; m < 4; ++m)
        a[m] = *reinterpret_cast<const bf16x8*>(&As[(wr * 64 + m * 16 + lr) * 64 + lk]);
#pragma unroll
      for (int n = 0; n < 2; ++n)
        b[n] = *reinterpret_cast<const bf16x8*>(&Bs[(wc * 32 + n * 16 + lr) * 64 + lk]);
#pragma unroll
      for (int m = 0; m < 4; ++m)
#pragma unroll
        for (int n = 0; n < 2; ++n)
          acc[m][n] = __builtin_amdgcn_mfma_f32_16x16x32_bf16(a[m], b[n], acc[m][n], 0, 0, 0);
    }
  }

  const int row0 = bm * 128 + wr * 64;
  const int col0 = bn * 64 + wc * 32;
#pragma unroll
  for (int m = 0; m < 4; ++m)
#pragma unroll
    for (int n = 0; n < 2; ++n)
#pragma unroll
      for (int j = 0; j < 4; ++j) {
        int r = row0 + m * 16 + (lane >> 4) * 4 + j;
        int c = col0 + n * 16 + (lane & 15);
        float v = acc[m][n][j];
        if (MODE == 0) {
          if (c < 768)  // Q pre-scaled by (1/8)*log2(e) for exp2-domain softmax
            ((unsigned short*)out0)[(size_t)r * 768 + c] = f2bf(v * 0.180336884f);
          else if (c < 1536)
            Kout[(size_t)r * 768 + (c - 768)] = f2bf(v);
          else
            Vt[(size_t)(c - 1536) * M + r] = f2bf(v);
        } else {
          ((float*)out0)[(size_t)r * N + c] = v;
        }
      }
}

// ---------------- attention helpers ----------------
__device__ __forceinline__ void stage_kv(const unsigned short* __restrict__ Kb,
                                         const unsigned short* __restrict__ Vt,
                                         unsigned short* Kbuf, unsigned short* Vbuf,
                                         int h, int st, int wid, int lane) {
  const int cg = lane & 7, rsub = (lane >> 3) & 7;
  const unsigned short* gK = Kb + (size_t)(st * 64) * C_DIM + h * 64;
  const unsigned short* gV = Vt + (size_t)(h * 64) * T_SEQ + st * 64;
#pragma unroll
  for (int c = 0; c < 2; ++c) {
    int seg = wid * 2 + c;
    int row = seg * 8 + rsub;
    GLD16(gK + (size_t)row * C_DIM + (cg ^ rsub) * 8, (char*)Kbuf + seg * 1024);
    GLD16(gV + (size_t)row * T_SEQ + (cg ^ rsub) * 8, (char*)Vbuf + seg * 1024);
  }
}

// chunk size 12 tiles; nst_total = 2qb+2; nch = ceil((2qb+2)/12)
__device__ __forceinline__ int nchunks(int q) { return (2 * q + 13) / 12; }
// partial sets for qb>=6 (nch>=2): 96 sets/head
__device__ __forceinline__ int part_off(int qb) {
  if (qb < 12) return (qb - 6) * 2;
  if (qb < 18) return 12 + (qb - 12) * 3;
  if (qb < 24) return 30 + (qb - 18) * 4;
  if (qb < 30) return 54 + (qb - 24) * 5;
  return 84 + (qb - 30) * 6;
}
// 1152 sets x 16KB: 768 in d_out (12.58MB exact), 384 in Xb region (6.29MB exact)
__device__ __forceinline__ unsigned short* part_ptr(char* pA, char* pB, int set) {
  return (set < 768) ? (unsigned short*)(pA + (size_t)set * 16384)
                     : (unsigned short*)(pB + (size_t)(set - 768) * 16384);
}

// ---------------- flash attention (causal, swapped QK^T, s-chunked) ----------------
// grid = (NH, 102): x = head (fastest dispatch dim) so qb-descending chunk
// slots in y dispatch longest-first across ALL heads (LPT makespan).
// global_load_lds staging (reg-staging spills: R4/R5); min-waves 3.
__global__ __launch_bounds__(256, 3)
void attn_fwd(const unsigned short* __restrict__ Qb,
              const unsigned short* __restrict__ Kb,
              const unsigned short* __restrict__ Vt,
              unsigned short* __restrict__ Y,
              char* __restrict__ partA, char* __restrict__ partB,
              float* __restrict__ ml) {
  __shared__ __align__(16) unsigned short Ks[2][64 * 64];
  __shared__ __align__(16) unsigned short Vs[2][64 * 64];  // [d][s]
  __shared__ __align__(16) unsigned short Ps[4][32 * 64];

  const int h = blockIdx.x;
  int qb = 0, ck = 0;
  {
    int idx = blockIdx.y;
    for (int q = 31; q >= 0; --q) {
      int nc = nchunks(q);
      if (idx < nc) { qb = q; ck = idx; break; }
      idx -= nc;
    }
  }
  const int nch = nchunks(qb);
  const int q0 = qb * 128;
  const int nst_total = 2 * qb + 2;
  const int st0 = ck * 12;
  const int st1 = (st0 + 12 < nst_total) ? st0 + 12 : nst_total;

  const int tid = threadIdx.x;
  const int wid = tid >> 6, lane = tid & 63;
  const int l15 = lane & 15, g = lane >> 4;
  const int sw = l15 & 7;
  const int qw = q0 + wid * 32;

  bf16x8 qf[2][2];
#pragma unroll
  for (int m = 0; m < 2; ++m)
#pragma unroll
    for (int kk = 0; kk < 2; ++kk)
      qf[m][kk] = *reinterpret_cast<const bf16x8*>(
          &Qb[(size_t)(qw + m * 16 + l15) * C_DIM + h * 64 + kk * 32 + g * 8]);

  f32x4 o[2][4] = {};  // O^T fragments: row=d, col=q
  float mrow[2] = {-1e30f, -1e30f};
  float lsum[2] = {0.f, 0.f};

  stage_kv(Kb, Vt, Ks[0], Vs[0], h, st0, wid, lane);
  int cur = 0;

  for (int st = st0; st < st1; ++st) {
    if (st + 1 < st1) {
      stage_kv(Kb, Vt, Ks[cur ^ 1], Vs[cur ^ 1], h, st + 1, wid, lane);
      asm volatile("s_waitcnt vmcnt(4)" ::: "memory");  // cur tile's 4 loads done
    } else {
      asm volatile("s_waitcnt vmcnt(0)" ::: "memory");
    }
    __builtin_amdgcn_s_barrier();

    const bool active = (st * 64) <= (qw + 31);
    if (active) {
      const unsigned short* K_ = Ks[cur];
      const unsigned short* V_ = Vs[cur];

      // S^T = K @ Q^T  (S in log2 domain: Q pre-scaled by 0.125*log2e)
      f32x4 sT[2][4] = {};
      __builtin_amdgcn_s_setprio(1);
#pragma unroll
      for (int kk = 0; kk < 2; ++kk) {
        bf16x8 kf[4];
#pragma unroll
        for (int n = 0; n < 4; ++n)
          kf[n] = *reinterpret_cast<const bf16x8*>(
              &K_[(n * 16 + l15) * 64 + (((kk * 4 + g) ^ sw) * 8)]);
#pragma unroll
        for (int m = 0; m < 2; ++m)
#pragma unroll
          for (int n = 0; n < 4; ++n)
            sT[m][n] = __builtin_amdgcn_mfma_f32_16x16x32_bf16(kf[n], qf[m][kk], sT[m][n], 0, 0, 0);
      }
      __builtin_amdgcn_s_setprio(0);

      unsigned short* Pw = Ps[wid];
#pragma unroll
      for (int m = 0; m < 2; ++m) {
        if (!(st * 64 + 63 <= qw + m * 16)) {
          // diagonal tile: apply causal mask (rare, wave-uniform branch)
          const int bound = (qw + m * 16 + l15) - st * 64;
#pragma unroll
          for (int n = 0; n < 4; ++n)
#pragma unroll
            for (int jj = 0; jj < 4; ++jj) {
              int sl = n * 16 + g * 4 + jj;
              if (sl > bound) sT[m][n][jj] = -1e30f;
            }
        }
        // tree max (3 levels; clang may fuse to v_max3)
        float vm[4];
#pragma unroll
        for (int n = 0; n < 4; ++n)
          vm[n] = fmaxf(fmaxf(sT[m][n][0], sT[m][n][1]), fmaxf(sT[m][n][2], sT[m][n][3]));
        float vmax = fmaxf(fmaxf(vm[0], vm[1]), fmaxf(vm[2], vm[3]));
        vmax = fmaxf(vmax, __shfl_xor(vmax, 16, 64));
        vmax = fmaxf(vmax, __shfl_xor(vmax, 32, 64));
        // defer-rescale (T13): keep old max while growth <= 8 (P bounded by 2^8)
        const bool defer = (__all(vmax <= mrow[m] + 8.0f) != 0);
        const float mnew = defer ? mrow[m] : fmaxf(mrow[m], vmax);
#pragma unroll
        for (int n = 0; n < 4; ++n)
#pragma unroll
          for (int jj = 0; jj < 4; ++jj)
            sT[m][n][jj] = E2(sT[m][n][jj] - mnew);
        // tree sum
        float sm[4];
#pragma unroll
        for (int n = 0; n < 4; ++n)
          sm[n] = (sT[m][n][0] + sT[m][n][1]) + (sT[m][n][2] + sT[m][n][3]);
        float ps = (sm[0] + sm[1]) + (sm[2] + sm[3]);
        ps += __shfl_xor(ps, 16, 64);
        ps += __shfl_xor(ps, 32, 64);
        if (defer) {
          lsum[m] += ps;
        } else {
          float alpha = E2(mrow[m] - mnew);
          lsum[m] = lsum[m] * alpha + ps;
          mrow[m] = mnew;
#pragma unroll
          for (int n2 = 0; n2 < 4; ++n2) o[m][n2] *= alpha;
        }
#pragma unroll
        for (int n = 0; n < 4; ++n) {
          uint2 pw;
          pw.x = cvtpk(sT[m][n][0], sT[m][n][1]);
          pw.y = cvtpk(sT[m][n][2], sT[m][n][3]);
          *reinterpret_cast<uint2*>(
              &Pw[(m * 16 + l15) * 64 + (((n * 2 + (g >> 1)) ^ sw) * 8) + (g & 1) * 4]) = pw;
        }
      }
      asm volatile("s_waitcnt lgkmcnt(0)" ::: "memory");

      // O^T += V^T @ P^T
      __builtin_amdgcn_s_setprio(1);
#pragma unroll
      for (int ks = 0; ks < 2; ++ks) {
        bf16x8 vf[4], pf[2];
#pragma unroll
        for (int n2 = 0; n2 < 4; ++n2)
          vf[n2] = *reinterpret_cast<const bf16x8*>(
              &V_[(n2 * 16 + l15) * 64 + (((ks * 4 + g) ^ sw) * 8)]);
#pragma unroll
        for (int m = 0; m < 2; ++m)
          pf[m] = *reinterpret_cast<const bf16x8*>(
              &Pw[(m * 16 + l15) * 64 + (((ks * 4 + g) ^ sw) * 8)]);
#pragma unroll
        for (int m = 0; m < 2; ++m)
#pragma unroll
          for (int n2 = 0; n2 < 4; ++n2)
            o[m][n2] = __builtin_amdgcn_mfma_f32_16x16x32_bf16(vf[n2], pf[m], o[m][n2], 0, 0, 0);
      }
      __builtin_amdgcn_s_setprio(0);
    }
    asm volatile("" ::: "memory");
    __builtin_amdgcn_s_barrier();
    cur ^= 1;
  }

  if (nch == 1) {
#pragma unroll
    for (int m = 0; m < 2; ++m) {
      float inv = 1.0f / lsum[m];
      int qg = qw + m * 16 + l15;
#pragma unroll
      for (int n2 = 0; n2 < 4; ++n2) {
        uint2 yk;
        yk.x = cvtpk(o[m][n2][0] * inv, o[m][n2][1] * inv);
        yk.y = cvtpk(o[m][n2][2] * inv, o[m][n2][3] * inv);
        *reinterpret_cast<uint2*>(&Y[(size_t)qg * C_DIM + h * 64 + n2 * 16 + g * 4]) = yk;
      }
    }
  } else {
    const int set = h * 96 + part_off(qb) + ck;
    unsigned short* po = part_ptr(partA, partB, set);
#pragma unroll
    for (int m = 0; m < 2; ++m) {
      int qL = wid * 32 + m * 16 + l15;
#pragma unroll
      for (int n2 = 0; n2 < 4; ++n2) {
        uint2 pk;
        pk.x = cvtpk(o[m][n2][0], o[m][n2][1]);
        pk.y = cvtpk(o[m][n2][2], o[m][n2][3]);
        *reinterpret_cast<uint2*>(&po[qL * 64 + n2 * 16 + g * 4]) = pk;
      }
      if (g == 0) {
        ml[(size_t)set * 256 + qL * 2] = mrow[m];
        ml[(size_t)set * 256 + qL * 2 + 1] = lsum[m];
      }
    }
  }
}

// ---------------- combine partials (exp2 domain) ----------------
// grid (26, NH): qb = 6 + bx
__global__ __launch_bounds__(256)
void attn_combine(char* __restrict__ partA, char* __restrict__ partB,
                  const float* __restrict__ ml, unsigned short* __restrict__ Y) {
  const int qb = 6 + blockIdx.x;
  const int h = blockIdx.y;
  const int nch = nchunks(qb);
  const int set0 = h * 96 + part_off(qb);
  const int t = threadIdx.x;
  const int r = t >> 1, dh = (t & 1) * 32;

  float mi[6], li[6];
  float M = -1e30f;
  for (int i = 0; i < nch; ++i) {
    mi[i] = ml[(size_t)(set0 + i) * 256 + r * 2];
    li[i] = ml[(size_t)(set0 + i) * 256 + r * 2 + 1];
    M = fmaxf(M, mi[i]);
  }
  float L = 0.f;
  float O[32];
#pragma unroll
  for (int d = 0; d < 32; ++d) O[d] = 0.f;
  for (int i = 0; i < nch; ++i) {
    float w = E2(mi[i] - M);
    L += li[i] * w;
    const unsigned short* po = part_ptr(partA, partB, set0 + i) + r * 64 + dh;
#pragma unroll
    for (int d4 = 0; d4 < 32; d4 += 4) {
      ushort4 v = *reinterpret_cast<const ushort4*>(po + d4);
      O[d4 + 0] += bf2f(v.x) * w;
      O[d4 + 1] += bf2f(v.y) * w;
      O[d4 + 2] += bf2f(v.z) * w;
      O[d4 + 3] += bf2f(v.w) * w;
    }
  }
  float inv = 1.0f / L;
  unsigned short* yp = Y + (size_t)(qb * 128 + r) * C_DIM + h * 64 + dh;
#pragma unroll
  for (int d4 = 0; d4 < 32; d4 += 4) {
    uint2 yk;
    yk.x = cvtpk(O[d4 + 0] * inv, O[d4 + 1] * inv);
    yk.y = cvtpk(O[d4 + 2] * inv, O[d4 + 3] * inv);
    *reinterpret_cast<uint2*>(yp + d4) = yk;
  }
}

// ---------------- launcher ----------------
extern "C" void kernel_launch(void* const* d_in, const int* in_sizes, int n_in,
                              void* d_out, int out_size, void* d_ws, size_t ws_size,
                              hipStream_t stream) {
  const float* x = (const float*)d_in[0];       // [4096][768]
  const float* w_attn = (const float*)d_in[1];  // [768][2304]
  const float* w_proj = (const float*)d_in[2];  // [768][768]
  float* out = (float*)d_out;                   // [4096][768] f32

  char* ws = (char*)d_ws;
  unsigned short* Xb   = (unsigned short*)(ws + 0);          // 6291456 B (dead after QKV -> part spill B: 384 sets exact)
  unsigned short* WaT  = (unsigned short*)(ws + 6291456);    // 3538944 B (dead after QKV -> ml 1.18MB)
  unsigned short* WpT  = (unsigned short*)(ws + 9830400);    // 1179648 B [768][768]
  unsigned short* Qb   = (unsigned short*)(ws + 11010048);   // 6291456 B [T][768]
  unsigned short* Kb   = (unsigned short*)(ws + 17301504);   // 6291456 B [T][768]
  unsigned short* Vt   = (unsigned short*)(ws + 23592960);   // 6291456 B [768][T]
  unsigned short* Yb   = (unsigned short*)(ws + 29884416);   // 6291456 B [T][768]

  char* partA = (char*)d_out;            // free during attention; overwritten by proj GEMM
  char* partB = (char*)ws;               // Xb region, dead after QKV GEMM
  float* mlp  = (float*)(ws + 6291456);  // WaT region, dead after QKV GEMM

  prep<<<5376, 256, 0, stream>>>(x, Xb, w_attn, WaT, w_proj, WpT);

  gemm_bt<0><<<(T_SEQ / 128) * (2304 / 64), 256, 0, stream>>>(
      Xb, WaT, (void*)Qb, Kb, Vt, T_SEQ, 2304, C_DIM);

  attn_fwd<<<dim3(NH, 102), 256, 0, stream>>>(Qb, Kb, Vt, Yb, partA, partB, mlp);
  attn_combine<<<dim3(26, NH), 256, 0, stream>>>(partA, partB, mlp, Yb);

  gemm_bt<1><<<(T_SEQ / 128) * (C_DIM / 64), 256, 0, stream>>>(
      Yb, WpT, (void*)out, nullptr, nullptr, T_SEQ, C_DIM, C_DIM);
}

// Round 13
// 137.792 us; speedup vs baseline: 1.0215x; 1.0019x over previous
//
#include <hip/hip_runtime.h>

// Causal self-attention: B=1, T=4096, C=768, H=12, hd=64
// f32 in/out, bf16 MFMA compute internally. Flash-decoding s-split.
// R13: attn V single-buffered (LDS 48->40KB, 4 blocks/CU; V(t+1) staged after
// end-barrier, vmcnt(2) covers K+V with K(t+1) in flight). proj GEMM 64x64
// tile (384->768 blocks; was 1.5 blocks/CU). Inner attn loop = R12 exactly.

typedef short bf16x8 __attribute__((ext_vector_type(8)));
typedef float f32x4 __attribute__((ext_vector_type(4)));

#define T_SEQ 4096
#define C_DIM 768
#define NH 12
#define HD 64

__device__ __forceinline__ unsigned short f2bf(float f) {
  union { float f; unsigned u; } v; v.f = f;
  unsigned r = v.u + 0x7FFFu + ((v.u >> 16) & 1u);
  return (unsigned short)(r >> 16);
}
__device__ __forceinline__ float bf2f(unsigned short u) {
  union { unsigned u; float f; } v; v.u = ((unsigned)u) << 16;
  return v.f;
}
__device__ __forceinline__ unsigned cvtpk(float a, float b) {
  unsigned r;
  asm("v_cvt_pk_bf16_f32 %0, %1, %2" : "=v"(r) : "v"(a), "v"(b));
  return r;
}
#define E2(x) __builtin_amdgcn_exp2f(x)

#define GLD16(g, l) __builtin_amdgcn_global_load_lds( \
    (const __attribute__((address_space(1))) void*)(g), \
    (__attribute__((address_space(3))) void*)(l), 16, 0, 0)

// ---------------- fused prep: f32->bf16 conv + 2 weight transposes ----------------
__device__ __forceinline__ void tr_body(const float* __restrict__ in,
                                        unsigned short* __restrict__ out,
                                        int R, int Cc, int bx, int by,
                                        float (*tile)[33]) {
  int tx = threadIdx.x & 31, ty = threadIdx.x >> 5;
#pragma unroll
  for (int i = 0; i < 32; i += 8)
    tile[ty + i][tx] = in[(size_t)(by * 32 + ty + i) * Cc + bx * 32 + tx];
  __syncthreads();
#pragma unroll
  for (int i = 0; i < 32; i += 8)
    out[(size_t)(bx * 32 + ty + i) * R + by * 32 + tx] = f2bf(tile[tx][ty + i]);
}

__global__ void prep(const float* __restrict__ x, unsigned short* __restrict__ Xb,
                     const float* __restrict__ w_attn, unsigned short* __restrict__ WaT,
                     const float* __restrict__ w_proj, unsigned short* __restrict__ WpT) {
  __shared__ float tile[32][33];
  const int bid = blockIdx.x;
  if (bid < 3072) {                       // conv x: 4096x768 f32 -> bf16
    int i = (bid * 256 + threadIdx.x) * 4;
    float4 v = *reinterpret_cast<const float4*>(x + i);
    ushort4 o;
    o.x = f2bf(v.x); o.y = f2bf(v.y); o.z = f2bf(v.z); o.w = f2bf(v.w);
    *reinterpret_cast<ushort4*>(Xb + i) = o;
  } else if (bid < 3072 + 1728) {         // w_attn^T: 768x2304 -> [2304][768]
    int b = bid - 3072;
    tr_body(w_attn, WaT, 768, 2304, b % 72, b / 72, tile);
  } else {                                // w_proj^T: 768x768 -> [768][768]
    int b = bid - 4800;
    tr_body(w_proj, WpT, 768, 768, b % 24, b / 24, tile);
  }
}

// ---------------- BT-GEMM: A[M][K] bf16 @ Bt[N][K] bf16 ----------------
// Templated tile; 1-D grid with bijective XCD swizzle.
template <int MODE, int BM, int BN>
__global__ __launch_bounds__(256, 4)
void gemm_bt(const unsigned short* __restrict__ A,
             const unsigned short* __restrict__ Bt,
             void* __restrict__ out0,
             unsigned short* __restrict__ Kout,
             unsigned short* __restrict__ Vt,
             int M, int N, int K) {
  __shared__ __align__(16) unsigned short As[BM * 64];
  __shared__ __align__(16) unsigned short Bs[BN * 64];
  constexpr int AM = BM / 32, AN = BN / 32;   // acc tile counts per wave
  const int nbn = N / BN;
  const int nwg = (M / BM) * nbn;
  const int cpx = nwg >> 3;               // nwg % 8 == 0 (1152, 768)
  const int swz = ((int)blockIdx.x & 7) * cpx + ((int)blockIdx.x >> 3);
  const int bm = swz / nbn, bn = swz % nbn;
  const int tid = threadIdx.x;
  const int wid = tid >> 6, lane = tid & 63;
  const int wr = wid >> 1, wc = wid & 1;
  const int lr = lane & 15;
  const int lk8 = (lane >> 4) * 8;
  const int rsub = lane >> 3, csub = (lane & 7) * 8;

  f32x4 acc[AM][AN] = {};

  const int nk = K / 64;
  for (int kt = 0; kt < nk; ++kt) {
    __syncthreads();
    {
      const unsigned short* gA = A + (size_t)(bm * BM) * K + kt * 64;
      const unsigned short* gB = Bt + (size_t)(bn * BN) * K + kt * 64;
#pragma unroll
      for (int c = 0; c < BM / 32; ++c) {
        int seg = wid * (BM / 32) + c;
        int row = seg * 8 + rsub;
        GLD16(gA + (size_t)row * K + csub, (char*)As + seg * 1024);
      }
#pragma unroll
      for (int c = 0; c < BN / 32; ++c) {
        int seg = wid * (BN / 32) + c;
        int row = seg * 8 + rsub;
        GLD16(gB + (size_t)row * K + csub, (char*)Bs + seg * 1024);
      }
    }
    __syncthreads();
#pragma unroll
    for (int kk = 0; kk < 2; ++kk) {
      bf16x8 a[AM], b[AN];
      int lk = kk * 32 + lk8;
#pragma unroll
      for (int m = 0; m < AM; ++m)
        a[m] = *reinterpret_cast<const bf16x8*>(&As[(wr * (BM / 2) + m * 16 + lr) * 64 + lk]);
#pragma unroll
      for (int n = 0; n < AN; ++n)
        b[n] = *reinterpret_cast<const bf16x8*>(&Bs[(wc * (BN / 2) + n * 16 + lr) * 64 + lk]);
#pragma unroll
      for (int m = 0; m < AM; ++m)
#pragma unroll
        for (int n = 0; n < AN; ++n)
          acc[m][n] = __builtin_amdgcn_mfma_f32_16x16x32_bf16(a[m], b[n], acc[m][n], 0, 0, 0);
    }
  }

  const int row0 = bm * BM + wr * (BM / 2);
  const int col0 = bn * BN + wc * (BN / 2);
#pragma unroll
  for (int m = 0; m < AM; ++m)
#pragma unroll
    for (int n = 0; n < AN; ++n)
#pragma unroll
      for (int j = 0; j < 4; ++j) {
        int r = row0 + m * 16 + (lane >> 4) * 4 + j;
        int c = col0 + n * 16 + (lane & 15);
        float v = acc[m][n][j];
        if (MODE == 0) {
          if (c < 768)  // Q pre-scaled by (1/8)*log2(e) for exp2-domain softmax
            ((unsigned short*)out0)[(size_t)r * 768 + c] = f2bf(v * 0.180336884f);
          else if (c < 1536)
            Kout[(size_t)r * 768 + (c - 768)] = f2bf(v);
          else
            Vt[(size_t)(c - 1536) * M + r] = f2bf(v);
        } else {
          ((float*)out0)[(size_t)r * N + c] = v;
        }
      }
}

// ---------------- attention helpers ----------------
__device__ __forceinline__ void stage_k(const unsigned short* __restrict__ Kb,
                                        unsigned short* Kbuf,
                                        int h, int st, int wid, int lane) {
  const int cg = lane & 7, rsub = (lane >> 3) & 7;
  const unsigned short* gK = Kb + (size_t)(st * 64) * C_DIM + h * 64;
#pragma unroll
  for (int c = 0; c < 2; ++c) {
    int seg = wid * 2 + c;
    int row = seg * 8 + rsub;
    GLD16(gK + (size_t)row * C_DIM + (cg ^ rsub) * 8, (char*)Kbuf + seg * 1024);
  }
}
__device__ __forceinline__ void stage_v(const unsigned short* __restrict__ Vt,
                                        unsigned short* Vbuf,
                                        int h, int st, int wid, int lane) {
  const int cg = lane & 7, rsub = (lane >> 3) & 7;
  const unsigned short* gV = Vt + (size_t)(h * 64) * T_SEQ + st * 64;
#pragma unroll
  for (int c = 0; c < 2; ++c) {
    int seg = wid * 2 + c;
    int row = seg * 8 + rsub;
    GLD16(gV + (size_t)row * T_SEQ + (cg ^ rsub) * 8, (char*)Vbuf + seg * 1024);
  }
}

// chunk size 12 tiles; nst_total = 2qb+2; nch = ceil((2qb+2)/12)
__device__ __forceinline__ int nchunks(int q) { return (2 * q + 13) / 12; }
// partial sets for qb>=6 (nch>=2): 96 sets/head
__device__ __forceinline__ int part_off(int qb) {
  if (qb < 12) return (qb - 6) * 2;
  if (qb < 18) return 12 + (qb - 12) * 3;
  if (qb < 24) return 30 + (qb - 18) * 4;
  if (qb < 30) return 54 + (qb - 24) * 5;
  return 84 + (qb - 30) * 6;
}
// 1152 sets x 16KB: 768 in d_out, 384 in Xb region
__device__ __forceinline__ unsigned short* part_ptr(char* pA, char* pB, int set) {
  return (set < 768) ? (unsigned short*)(pA + (size_t)set * 16384)
                     : (unsigned short*)(pB + (size_t)(set - 768) * 16384);
}

// ---------------- flash attention (causal, swapped QK^T, s-chunked) ----------------
// grid = (NH, 102): x = head (fastest dispatch dim) -> LPT across heads.
// K double-buffered, V single-buffered (staged after end barrier): LDS 40KB.
__global__ __launch_bounds__(256, 3)
void attn_fwd(const unsigned short* __restrict__ Qb,
              const unsigned short* __restrict__ Kb,
              const unsigned short* __restrict__ Vt,
              unsigned short* __restrict__ Y,
              char* __restrict__ partA, char* __restrict__ partB,
              float* __restrict__ ml) {
  __shared__ __align__(16) unsigned short Ks[2][64 * 64];
  __shared__ __align__(16) unsigned short Vs[64 * 64];  // [d][s], single buffer
  __shared__ __align__(16) unsigned short Ps[4][32 * 64];

  const int h = blockIdx.x;
  int qb = 0, ck = 0;
  {
    int idx = blockIdx.y;
    for (int q = 31; q >= 0; --q) {
      int nc = nchunks(q);
      if (idx < nc) { qb = q; ck = idx; break; }
      idx -= nc;
    }
  }
  const int nch = nchunks(qb);
  const int q0 = qb * 128;
  const int nst_total = 2 * qb + 2;
  const int st0 = ck * 12;
  const int st1 = (st0 + 12 < nst_total) ? st0 + 12 : nst_total;

  const int tid = threadIdx.x;
  const int wid = tid >> 6, lane = tid & 63;
  const int l15 = lane & 15, g = lane >> 4;
  const int sw = l15 & 7;
  const int qw = q0 + wid * 32;

  bf16x8 qf[2][2];
#pragma unroll
  for (int m = 0; m < 2; ++m)
#pragma unroll
    for (int kk = 0; kk < 2; ++kk)
      qf[m][kk] = *reinterpret_cast<const bf16x8*>(
          &Qb[(size_t)(qw + m * 16 + l15) * C_DIM + h * 64 + kk * 32 + g * 8]);

  f32x4 o[2][4] = {};  // O^T fragments: row=d, col=q
  float mrow[2] = {-1e30f, -1e30f};
  float lsum[2] = {0.f, 0.f};

  stage_k(Kb, Ks[0], h, st0, wid, lane);
  stage_v(Vt, Vs, h, st0, wid, lane);
  int cur = 0;

  for (int st = st0; st < st1; ++st) {
    const bool haveNext = (st + 1 < st1);
    if (haveNext) {
      stage_k(Kb, Ks[cur ^ 1], h, st + 1, wid, lane);
      // queue: [K(t):2, V(t):2, K(t+1):2] -> wait K(t),V(t); K(t+1) in flight
      asm volatile("s_waitcnt vmcnt(2)" ::: "memory");
    } else {
      asm volatile("s_waitcnt vmcnt(0)" ::: "memory");
    }
    __builtin_amdgcn_s_barrier();

    const bool active = (st * 64) <= (qw + 31);
    if (active) {
      const unsigned short* K_ = Ks[cur];

      // S^T = K @ Q^T  (S in log2 domain: Q pre-scaled by 0.125*log2e)
      f32x4 sT[2][4] = {};
      __builtin_amdgcn_s_setprio(1);
#pragma unroll
      for (int kk = 0; kk < 2; ++kk) {
        bf16x8 kf[4];
#pragma unroll
        for (int n = 0; n < 4; ++n)
          kf[n] = *reinterpret_cast<const bf16x8*>(
              &K_[(n * 16 + l15) * 64 + (((kk * 4 + g) ^ sw) * 8)]);
#pragma unroll
        for (int m = 0; m < 2; ++m)
#pragma unroll
          for (int n = 0; n < 4; ++n)
            sT[m][n] = __builtin_amdgcn_mfma_f32_16x16x32_bf16(kf[n], qf[m][kk], sT[m][n], 0, 0, 0);
      }
      __builtin_amdgcn_s_setprio(0);

      unsigned short* Pw = Ps[wid];
#pragma unroll
      for (int m = 0; m < 2; ++m) {
        if (!(st * 64 + 63 <= qw + m * 16)) {
          // diagonal tile: apply causal mask (rare, wave-uniform branch)
          const int bound = (qw + m * 16 + l15) - st * 64;
#pragma unroll
          for (int n = 0; n < 4; ++n)
#pragma unroll
            for (int jj = 0; jj < 4; ++jj) {
              int sl = n * 16 + g * 4 + jj;
              if (sl > bound) sT[m][n][jj] = -1e30f;
            }
        }
        // tree max
        float vm[4];
#pragma unroll
        for (int n = 0; n < 4; ++n)
          vm[n] = fmaxf(fmaxf(sT[m][n][0], sT[m][n][1]), fmaxf(sT[m][n][2], sT[m][n][3]));
        float vmax = fmaxf(fmaxf(vm[0], vm[1]), fmaxf(vm[2], vm[3]));
        vmax = fmaxf(vmax, __shfl_xor(vmax, 16, 64));
        vmax = fmaxf(vmax, __shfl_xor(vmax, 32, 64));
        // defer-rescale (T13): keep old max while growth <= 8 (P bounded by 2^8)
        const bool defer = (__all(vmax <= mrow[m] + 8.0f) != 0);
        const float mnew = defer ? mrow[m] : fmaxf(mrow[m], vmax);
#pragma unroll
        for (int n = 0; n < 4; ++n)
#pragma unroll
          for (int jj = 0; jj < 4; ++jj)
            sT[m][n][jj] = E2(sT[m][n][jj] - mnew);
        // tree sum
        float sm[4];
#pragma unroll
        for (int n = 0; n < 4; ++n)
          sm[n] = (sT[m][n][0] + sT[m][n][1]) + (sT[m][n][2] + sT[m][n][3]);
        float ps = (sm[0] + sm[1]) + (sm[2] + sm[3]);
        ps += __shfl_xor(ps, 16, 64);
        ps += __shfl_xor(ps, 32, 64);
        if (defer) {
          lsum[m] += ps;
        } else {
          float alpha = E2(mrow[m] - mnew);
          lsum[m] = lsum[m] * alpha + ps;
          mrow[m] = mnew;
#pragma unroll
          for (int n2 = 0; n2 < 4; ++n2) o[m][n2] *= alpha;
        }
#pragma unroll
        for (int n = 0; n < 4; ++n) {
          uint2 pw;
          pw.x = cvtpk(sT[m][n][0], sT[m][n][1]);
          pw.y = cvtpk(sT[m][n][2], sT[m][n][3]);
          *reinterpret_cast<uint2*>(
              &Pw[(m * 16 + l15) * 64 + (((n * 2 + (g >> 1)) ^ sw) * 8) + (g & 1) * 4]) = pw;
        }
      }
      asm volatile("s_waitcnt lgkmcnt(0)" ::: "memory");

      // O^T += V^T @ P^T
      __builtin_amdgcn_s_setprio(1);
#pragma unroll
      for (int ks = 0; ks < 2; ++ks) {
        bf16x8 vf[4], pf[2];
#pragma unroll
        for (int n2 = 0; n2 < 4; ++n2)
          vf[n2] = *reinterpret_cast<const bf16x8*>(
              &Vs[(n2 * 16 + l15) * 64 + (((ks * 4 + g) ^ sw) * 8)]);
#pragma unroll
        for (int m = 0; m < 2; ++m)
          pf[m] = *reinterpret_cast<const bf16x8*>(
              &Pw[(m * 16 + l15) * 64 + (((ks * 4 + g) ^ sw) * 8)]);
#pragma unroll
        for (int m = 0; m < 2; ++m)
#pragma unroll
          for (int n2 = 0; n2 < 4; ++n2)
            o[m][n2] = __builtin_amdgcn_mfma_f32_16x16x32_bf16(vf[n2], pf[m], o[m][n2], 0, 0, 0);
      }
      __builtin_amdgcn_s_setprio(0);
    }
    asm volatile("" ::: "memory");
    __builtin_amdgcn_s_barrier();
    // V(t+1) staged only after ALL waves passed the barrier (done reading Vs)
    if (haveNext) stage_v(Vt, Vs, h, st + 1, wid, lane);
    cur ^= 1;
  }

  if (nch == 1) {
#pragma unroll
    for (int m = 0; m < 2; ++m) {
      float inv = 1.0f / lsum[m];
      int qg = qw + m * 16 + l15;
#pragma unroll
      for (int n2 = 0; n2 < 4; ++n2) {
        uint2 yk;
        yk.x = cvtpk(o[m][n2][0] * inv, o[m][n2][1] * inv);
        yk.y = cvtpk(o[m][n2][2] * inv, o[m][n2][3] * inv);
        *reinterpret_cast<uint2*>(&Y[(size_t)qg * C_DIM + h * 64 + n2 * 16 + g * 4]) = yk;
      }
    }
  } else {
    const int set = h * 96 + part_off(qb) + ck;
    unsigned short* po = part_ptr(partA, partB, set);
#pragma unroll
    for (int m = 0; m < 2; ++m) {
      int qL = wid * 32 + m * 16 + l15;
#pragma unroll
      for (int n2 = 0; n2 < 4; ++n2) {
        uint2 pk;
        pk.x = cvtpk(o[m][n2][0], o[m][n2][1]);
        pk.y = cvtpk(o[m][n2][2], o[m][n2][3]);
        *reinterpret_cast<uint2*>(&po[qL * 64 + n2 * 16 + g * 4]) = pk;
      }
      if (g == 0) {
        ml[(size_t)set * 256 + qL * 2] = mrow[m];
        ml[(size_t)set * 256 + qL * 2 + 1] = lsum[m];
      }
    }
  }
}

// ---------------- combine partials (exp2 domain) ----------------
// grid (26, NH): qb = 6 + bx
__global__ __launch_bounds__(256)
void attn_combine(char* __restrict__ partA, char* __restrict__ partB,
                  const float* __restrict__ ml, unsigned short* __restrict__ Y) {
  const int qb = 6 + blockIdx.x;
  const int h = blockIdx.y;
  const int nch = nchunks(qb);
  const int set0 = h * 96 + part_off(qb);
  const int t = threadIdx.x;
  const int r = t >> 1, dh = (t & 1) * 32;

  float mi[6], li[6];
  float M = -1e30f;
  for (int i = 0; i < nch; ++i) {
    mi[i] = ml[(size_t)(set0 + i) * 256 + r * 2];
    li[i] = ml[(size_t)(set0 + i) * 256 + r * 2 + 1];
    M = fmaxf(M, mi[i]);
  }
  float L = 0.f;
  float O[32];
#pragma unroll
  for (int d = 0; d < 32; ++d) O[d] = 0.f;
  for (int i = 0; i < nch; ++i) {
    float w = E2(mi[i] - M);
    L += li[i] * w;
    const unsigned short* po = part_ptr(partA, partB, set0 + i) + r * 64 + dh;
#pragma unroll
    for (int d4 = 0; d4 < 32; d4 += 4) {
      ushort4 v = *reinterpret_cast<const ushort4*>(po + d4);
      O[d4 + 0] += bf2f(v.x) * w;
      O[d4 + 1] += bf2f(v.y) * w;
      O[d4 + 2] += bf2f(v.z) * w;
      O[d4 + 3] += bf2f(v.w) * w;
    }
  }
  float inv = 1.0f / L;
  unsigned short* yp = Y + (size_t)(qb * 128 + r) * C_DIM + h * 64 + dh;
#pragma unroll
  for (int d4 = 0; d4 < 32; d4 += 4) {
    uint2 yk;
    yk.x = cvtpk(O[d4 + 0] * inv, O[d4 + 1] * inv);
    yk.y = cvtpk(O[d4 + 2] * inv, O[d4 + 3] * inv);
    *reinterpret_cast<uint2*>(yp + d4) = yk;
  }
}

// ---------------- launcher ----------------
extern "C" void kernel_launch(void* const* d_in, const int* in_sizes, int n_in,
                              void* d_out, int out_size, void* d_ws, size_t ws_size,
                              hipStream_t stream) {
  const float* x = (const float*)d_in[0];       // [4096][768]
  const float* w_attn = (const float*)d_in[1];  // [768][2304]
  const float* w_proj = (const float*)d_in[2];  // [768][768]
  float* out = (float*)d_out;                   // [4096][768] f32

  char* ws = (char*)d_ws;
  unsigned short* Xb   = (unsigned short*)(ws + 0);          // 6291456 B (dead after QKV -> part spill B)
  unsigned short* WaT  = (unsigned short*)(ws + 6291456);    // 3538944 B (dead after QKV -> ml)
  unsigned short* WpT  = (unsigned short*)(ws + 9830400);    // 1179648 B [768][768]
  unsigned short* Qb   = (unsigned short*)(ws + 11010048);   // 6291456 B [T][768]
  unsigned short* Kb   = (unsigned short*)(ws + 17301504);   // 6291456 B [T][768]
  unsigned short* Vt   = (unsigned short*)(ws + 23592960);   // 6291456 B [768][T]
  unsigned short* Yb   = (unsigned short*)(ws + 29884416);   // 6291456 B [T][768]

  char* partA = (char*)d_out;            // free during attention; overwritten by proj GEMM
  char* partB = (char*)ws;               // Xb region, dead after QKV GEMM
  float* mlp  = (float*)(ws + 6291456);  // WaT region, dead after QKV GEMM

  prep<<<5376, 256, 0, stream>>>(x, Xb, w_attn, WaT, w_proj, WpT);

  gemm_bt<0, 128, 64><<<(T_SEQ / 128) * (2304 / 64), 256, 0, stream>>>(
      Xb, WaT, (void*)Qb, Kb, Vt, T_SEQ, 2304, C_DIM);

  attn_fwd<<<dim3(NH, 102), 256, 0, stream>>>(Qb, Kb, Vt, Yb, partA, partB, mlp);
  attn_combine<<<dim3(26, NH), 256, 0, stream>>>(partA, partB, mlp, Yb);

  gemm_bt<1, 64, 64><<<(T_SEQ / 64) * (C_DIM / 64), 256, 0, stream>>>(
      Yb, WpT, (void*)out, nullptr, nullptr, T_SEQ, C_DIM, C_DIM);
}

// Round 14
// 132.054 us; speedup vs baseline: 1.0659x; 1.0435x over previous
//
#include <hip/hip_runtime.h>

// Causal self-attention: B=1, T=4096, C=768, H=12, hd=64
// f32 in/out, bf16 MFMA compute internally. Flash-decoding s-split.
// R14: softmax denominator via ones-row MFMA (po = mfma(ones, pf, po)) --
// deletes per-iter tree-sum + 2 shfl from the serial VALU chain; denominator
// now consistent with bf16 P numerator. Everything else frozen at R13.

typedef short bf16x8 __attribute__((ext_vector_type(8)));
typedef float f32x4 __attribute__((ext_vector_type(4)));

#define T_SEQ 4096
#define C_DIM 768
#define NH 12
#define HD 64

__device__ __forceinline__ unsigned short f2bf(float f) {
  union { float f; unsigned u; } v; v.f = f;
  unsigned r = v.u + 0x7FFFu + ((v.u >> 16) & 1u);
  return (unsigned short)(r >> 16);
}
__device__ __forceinline__ float bf2f(unsigned short u) {
  union { unsigned u; float f; } v; v.u = ((unsigned)u) << 16;
  return v.f;
}
__device__ __forceinline__ unsigned cvtpk(float a, float b) {
  unsigned r;
  asm("v_cvt_pk_bf16_f32 %0, %1, %2" : "=v"(r) : "v"(a), "v"(b));
  return r;
}
#define E2(x) __builtin_amdgcn_exp2f(x)

#define GLD16(g, l) __builtin_amdgcn_global_load_lds( \
    (const __attribute__((address_space(1))) void*)(g), \
    (__attribute__((address_space(3))) void*)(l), 16, 0, 0)

// ---------------- fused prep: f32->bf16 conv + 2 weight transposes ----------------
__device__ __forceinline__ void tr_body(const float* __restrict__ in,
                                        unsigned short* __restrict__ out,
                                        int R, int Cc, int bx, int by,
                                        float (*tile)[33]) {
  int tx = threadIdx.x & 31, ty = threadIdx.x >> 5;
#pragma unroll
  for (int i = 0; i < 32; i += 8)
    tile[ty + i][tx] = in[(size_t)(by * 32 + ty + i) * Cc + bx * 32 + tx];
  __syncthreads();
#pragma unroll
  for (int i = 0; i < 32; i += 8)
    out[(size_t)(bx * 32 + ty + i) * R + by * 32 + tx] = f2bf(tile[tx][ty + i]);
}

__global__ void prep(const float* __restrict__ x, unsigned short* __restrict__ Xb,
                     const float* __restrict__ w_attn, unsigned short* __restrict__ WaT,
                     const float* __restrict__ w_proj, unsigned short* __restrict__ WpT) {
  __shared__ float tile[32][33];
  const int bid = blockIdx.x;
  if (bid < 3072) {                       // conv x: 4096x768 f32 -> bf16
    int i = (bid * 256 + threadIdx.x) * 4;
    float4 v = *reinterpret_cast<const float4*>(x + i);
    ushort4 o;
    o.x = f2bf(v.x); o.y = f2bf(v.y); o.z = f2bf(v.z); o.w = f2bf(v.w);
    *reinterpret_cast<ushort4*>(Xb + i) = o;
  } else if (bid < 3072 + 1728) {         // w_attn^T: 768x2304 -> [2304][768]
    int b = bid - 3072;
    tr_body(w_attn, WaT, 768, 2304, b % 72, b / 72, tile);
  } else {                                // w_proj^T: 768x768 -> [768][768]
    int b = bid - 4800;
    tr_body(w_proj, WpT, 768, 768, b % 24, b / 24, tile);
  }
}

// ---------------- BT-GEMM: A[M][K] bf16 @ Bt[N][K] bf16 ----------------
// Templated tile; 1-D grid with bijective XCD swizzle.
template <int MODE, int BM, int BN>
__global__ __launch_bounds__(256, 4)
void gemm_bt(const unsigned short* __restrict__ A,
             const unsigned short* __restrict__ Bt,
             void* __restrict__ out0,
             unsigned short* __restrict__ Kout,
             unsigned short* __restrict__ Vt,
             int M, int N, int K) {
  __shared__ __align__(16) unsigned short As[BM * 64];
  __shared__ __align__(16) unsigned short Bs[BN * 64];
  constexpr int AM = BM / 32, AN = BN / 32;   // acc tile counts per wave
  const int nbn = N / BN;
  const int nwg = (M / BM) * nbn;
  const int cpx = nwg >> 3;               // nwg % 8 == 0 (1152, 768)
  const int swz = ((int)blockIdx.x & 7) * cpx + ((int)blockIdx.x >> 3);
  const int bm = swz / nbn, bn = swz % nbn;
  const int tid = threadIdx.x;
  const int wid = tid >> 6, lane = tid & 63;
  const int wr = wid >> 1, wc = wid & 1;
  const int lr = lane & 15;
  const int lk8 = (lane >> 4) * 8;
  const int rsub = lane >> 3, csub = (lane & 7) * 8;

  f32x4 acc[AM][AN] = {};

  const int nk = K / 64;
  for (int kt = 0; kt < nk; ++kt) {
    __syncthreads();
    {
      const unsigned short* gA = A + (size_t)(bm * BM) * K + kt * 64;
      const unsigned short* gB = Bt + (size_t)(bn * BN) * K + kt * 64;
#pragma unroll
      for (int c = 0; c < BM / 32; ++c) {
        int seg = wid * (BM / 32) + c;
        int row = seg * 8 + rsub;
        GLD16(gA + (size_t)row * K + csub, (char*)As + seg * 1024);
      }
#pragma unroll
      for (int c = 0; c < BN / 32; ++c) {
        int seg = wid * (BN / 32) + c;
        int row = seg * 8 + rsub;
        GLD16(gB + (size_t)row * K + csub, (char*)Bs + seg * 1024);
      }
    }
    __syncthreads();
#pragma unroll
    for (int kk = 0; kk < 2; ++kk) {
      bf16x8 a[AM], b[AN];
      int lk = kk * 32 + lk8;
#pragma unroll
      for (int m = 0; m < AM; ++m)
        a[m] = *reinterpret_cast<const bf16x8*>(&As[(wr * (BM / 2) + m * 16 + lr) * 64 + lk]);
#pragma unroll
      for (int n = 0; n < AN; ++n)
        b[n] = *reinterpret_cast<const bf16x8*>(&Bs[(wc * (BN / 2) + n * 16 + lr) * 64 + lk]);
#pragma unroll
      for (int m = 0; m < AM; ++m)
#pragma unroll
        for (int n = 0; n < AN; ++n)
          acc[m][n] = __builtin_amdgcn_mfma_f32_16x16x32_bf16(a[m], b[n], acc[m][n], 0, 0, 0);
    }
  }

  const int row0 = bm * BM + wr * (BM / 2);
  const int col0 = bn * BN + wc * (BN / 2);
#pragma unroll
  for (int m = 0; m < AM; ++m)
#pragma unroll
    for (int n = 0; n < AN; ++n)
#pragma unroll
      for (int j = 0; j < 4; ++j) {
        int r = row0 + m * 16 + (lane >> 4) * 4 + j;
        int c = col0 + n * 16 + (lane & 15);
        float v = acc[m][n][j];
        if (MODE == 0) {
          if (c < 768)  // Q pre-scaled by (1/8)*log2(e) for exp2-domain softmax
            ((unsigned short*)out0)[(size_t)r * 768 + c] = f2bf(v * 0.180336884f);
          else if (c < 1536)
            Kout[(size_t)r * 768 + (c - 768)] = f2bf(v);
          else
            Vt[(size_t)(c - 1536) * M + r] = f2bf(v);
        } else {
          ((float*)out0)[(size_t)r * N + c] = v;
        }
      }
}

// ---------------- attention helpers ----------------
__device__ __forceinline__ void stage_k(const unsigned short* __restrict__ Kb,
                                        unsigned short* Kbuf,
                                        int h, int st, int wid, int lane) {
  const int cg = lane & 7, rsub = (lane >> 3) & 7;
  const unsigned short* gK = Kb + (size_t)(st * 64) * C_DIM + h * 64;
#pragma unroll
  for (int c = 0; c < 2; ++c) {
    int seg = wid * 2 + c;
    int row = seg * 8 + rsub;
    GLD16(gK + (size_t)row * C_DIM + (cg ^ rsub) * 8, (char*)Kbuf + seg * 1024);
  }
}
__device__ __forceinline__ void stage_v(const unsigned short* __restrict__ Vt,
                                        unsigned short* Vbuf,
                                        int h, int st, int wid, int lane) {
  const int cg = lane & 7, rsub = (lane >> 3) & 7;
  const unsigned short* gV = Vt + (size_t)(h * 64) * T_SEQ + st * 64;
#pragma unroll
  for (int c = 0; c < 2; ++c) {
    int seg = wid * 2 + c;
    int row = seg * 8 + rsub;
    GLD16(gV + (size_t)row * T_SEQ + (cg ^ rsub) * 8, (char*)Vbuf + seg * 1024);
  }
}

// chunk size 12 tiles; nst_total = 2qb+2; nch = ceil((2qb+2)/12)
__device__ __forceinline__ int nchunks(int q) { return (2 * q + 13) / 12; }
// partial sets for qb>=6 (nch>=2): 96 sets/head
__device__ __forceinline__ int part_off(int qb) {
  if (qb < 12) return (qb - 6) * 2;
  if (qb < 18) return 12 + (qb - 12) * 3;
  if (qb < 24) return 30 + (qb - 18) * 4;
  if (qb < 30) return 54 + (qb - 24) * 5;
  return 84 + (qb - 30) * 6;
}
// 1152 sets x 16KB: 768 in d_out, 384 in Xb region
__device__ __forceinline__ unsigned short* part_ptr(char* pA, char* pB, int set) {
  return (set < 768) ? (unsigned short*)(pA + (size_t)set * 16384)
                     : (unsigned short*)(pB + (size_t)(set - 768) * 16384);
}

// ---------------- flash attention (causal, swapped QK^T, s-chunked) ----------------
// grid = (NH, 102): x = head (fastest dispatch dim) -> LPT across heads.
// K double-buffered, V single-buffered (staged after end barrier): LDS 40KB.
__global__ __launch_bounds__(256, 3)
void attn_fwd(const unsigned short* __restrict__ Qb,
              const unsigned short* __restrict__ Kb,
              const unsigned short* __restrict__ Vt,
              unsigned short* __restrict__ Y,
              char* __restrict__ partA, char* __restrict__ partB,
              float* __restrict__ ml) {
  __shared__ __align__(16) unsigned short Ks[2][64 * 64];
  __shared__ __align__(16) unsigned short Vs[64 * 64];  // [d][s], single buffer
  __shared__ __align__(16) unsigned short Ps[4][32 * 64];

  const int h = blockIdx.x;
  int qb = 0, ck = 0;
  {
    int idx = blockIdx.y;
    for (int q = 31; q >= 0; --q) {
      int nc = nchunks(q);
      if (idx < nc) { qb = q; ck = idx; break; }
      idx -= nc;
    }
  }
  const int nch = nchunks(qb);
  const int q0 = qb * 128;
  const int nst_total = 2 * qb + 2;
  const int st0 = ck * 12;
  const int st1 = (st0 + 12 < nst_total) ? st0 + 12 : nst_total;

  const int tid = threadIdx.x;
  const int wid = tid >> 6, lane = tid & 63;
  const int l15 = lane & 15, g = lane >> 4;
  const int sw = l15 & 7;
  const int qw = q0 + wid * 32;

  bf16x8 qf[2][2];
#pragma unroll
  for (int m = 0; m < 2; ++m)
#pragma unroll
    for (int kk = 0; kk < 2; ++kk)
      qf[m][kk] = *reinterpret_cast<const bf16x8*>(
          &Qb[(size_t)(qw + m * 16 + l15) * C_DIM + h * 64 + kk * 32 + g * 8]);

  // all-ones bf16 A-fragment for the denominator MFMA (bf16 1.0 = 0x3F80)
  bf16x8 ones;
#pragma unroll
  for (int e = 0; e < 8; ++e) ones[e] = (short)0x3F80;

  f32x4 o[2][4] = {};  // O^T fragments: row=d, col=q
  f32x4 po[2] = {};    // denominator accumulator: every reg = sum_s P[q][s]
  float mrow[2] = {-1e30f, -1e30f};

  stage_k(Kb, Ks[0], h, st0, wid, lane);
  stage_v(Vt, Vs, h, st0, wid, lane);
  int cur = 0;

  for (int st = st0; st < st1; ++st) {
    const bool haveNext = (st + 1 < st1);
    if (haveNext) {
      stage_k(Kb, Ks[cur ^ 1], h, st + 1, wid, lane);
      // queue: [K(t):2, V(t):2, K(t+1):2] -> wait K(t),V(t); K(t+1) in flight
      asm volatile("s_waitcnt vmcnt(2)" ::: "memory");
    } else {
      asm volatile("s_waitcnt vmcnt(0)" ::: "memory");
    }
    __builtin_amdgcn_s_barrier();

    const bool active = (st * 64) <= (qw + 31);
    if (active) {
      const unsigned short* K_ = Ks[cur];

      // S^T = K @ Q^T  (S in log2 domain: Q pre-scaled by 0.125*log2e)
      f32x4 sT[2][4] = {};
      __builtin_amdgcn_s_setprio(1);
#pragma unroll
      for (int kk = 0; kk < 2; ++kk) {
        bf16x8 kf[4];
#pragma unroll
        for (int n = 0; n < 4; ++n)
          kf[n] = *reinterpret_cast<const bf16x8*>(
              &K_[(n * 16 + l15) * 64 + (((kk * 4 + g) ^ sw) * 8)]);
#pragma unroll
        for (int m = 0; m < 2; ++m)
#pragma unroll
          for (int n = 0; n < 4; ++n)
            sT[m][n] = __builtin_amdgcn_mfma_f32_16x16x32_bf16(kf[n], qf[m][kk], sT[m][n], 0, 0, 0);
      }
      __builtin_amdgcn_s_setprio(0);

      unsigned short* Pw = Ps[wid];
#pragma unroll
      for (int m = 0; m < 2; ++m) {
        if (!(st * 64 + 63 <= qw + m * 16)) {
          // diagonal tile: apply causal mask (rare, wave-uniform branch)
          const int bound = (qw + m * 16 + l15) - st * 64;
#pragma unroll
          for (int n = 0; n < 4; ++n)
#pragma unroll
            for (int jj = 0; jj < 4; ++jj) {
              int sl = n * 16 + g * 4 + jj;
              if (sl > bound) sT[m][n][jj] = -1e30f;
            }
        }
        // tree max
        float vm[4];
#pragma unroll
        for (int n = 0; n < 4; ++n)
          vm[n] = fmaxf(fmaxf(sT[m][n][0], sT[m][n][1]), fmaxf(sT[m][n][2], sT[m][n][3]));
        float vmax = fmaxf(fmaxf(vm[0], vm[1]), fmaxf(vm[2], vm[3]));
        vmax = fmaxf(vmax, __shfl_xor(vmax, 16, 64));
        vmax = fmaxf(vmax, __shfl_xor(vmax, 32, 64));
        // defer-rescale (T13): keep old max while growth <= 8 (P bounded by 2^8)
        const bool defer = (__all(vmax <= mrow[m] + 8.0f) != 0);
        const float mnew = defer ? mrow[m] : fmaxf(mrow[m], vmax);
#pragma unroll
        for (int n = 0; n < 4; ++n)
#pragma unroll
          for (int jj = 0; jj < 4; ++jj)
            sT[m][n][jj] = E2(sT[m][n][jj] - mnew);
        if (!defer) {
          float alpha = E2(mrow[m] - mnew);
          mrow[m] = mnew;
#pragma unroll
          for (int n2 = 0; n2 < 4; ++n2) o[m][n2] *= alpha;
          po[m] *= alpha;
        }
#pragma unroll
        for (int n = 0; n < 4; ++n) {
          uint2 pw;
          pw.x = cvtpk(sT[m][n][0], sT[m][n][1]);
          pw.y = cvtpk(sT[m][n][2], sT[m][n][3]);
          *reinterpret_cast<uint2*>(
              &Pw[(m * 16 + l15) * 64 + (((n * 2 + (g >> 1)) ^ sw) * 8) + (g & 1) * 4]) = pw;
        }
      }
      asm volatile("s_waitcnt lgkmcnt(0)" ::: "memory");

      // O^T += V^T @ P^T ; denominator += ones @ P^T (matrix-pipe row-sum)
      __builtin_amdgcn_s_setprio(1);
#pragma unroll
      for (int ks = 0; ks < 2; ++ks) {
        bf16x8 vf[4], pf[2];
#pragma unroll
        for (int n2 = 0; n2 < 4; ++n2)
          vf[n2] = *reinterpret_cast<const bf16x8*>(
              &Vs[(n2 * 16 + l15) * 64 + (((ks * 4 + g) ^ sw) * 8)]);
#pragma unroll
        for (int m = 0; m < 2; ++m)
          pf[m] = *reinterpret_cast<const bf16x8*>(
              &Pw[(m * 16 + l15) * 64 + (((ks * 4 + g) ^ sw) * 8)]);
#pragma unroll
        for (int m = 0; m < 2; ++m) {
#pragma unroll
          for (int n2 = 0; n2 < 4; ++n2)
            o[m][n2] = __builtin_amdgcn_mfma_f32_16x16x32_bf16(vf[n2], pf[m], o[m][n2], 0, 0, 0);
          po[m] = __builtin_amdgcn_mfma_f32_16x16x32_bf16(ones, pf[m], po[m], 0, 0, 0);
        }
      }
      __builtin_amdgcn_s_setprio(0);
    }
    asm volatile("" ::: "memory");
    __builtin_amdgcn_s_barrier();
    // V(t+1) staged only after ALL waves passed the barrier (done reading Vs)
    if (haveNext) stage_v(Vt, Vs, h, st + 1, wid, lane);
    cur ^= 1;
  }

  if (nch == 1) {
#pragma unroll
    for (int m = 0; m < 2; ++m) {
      float inv = 1.0f / po[m][0];
      int qg = qw + m * 16 + l15;
#pragma unroll
      for (int n2 = 0; n2 < 4; ++n2) {
        uint2 yk;
        yk.x = cvtpk(o[m][n2][0] * inv, o[m][n2][1] * inv);
        yk.y = cvtpk(o[m][n2][2] * inv, o[m][n2][3] * inv);
        *reinterpret_cast<uint2*>(&Y[(size_t)qg * C_DIM + h * 64 + n2 * 16 + g * 4]) = yk;
      }
    }
  } else {
    const int set = h * 96 + part_off(qb) + ck;
    unsigned short* po_ = part_ptr(partA, partB, set);
#pragma unroll
    for (int m = 0; m < 2; ++m) {
      int qL = wid * 32 + m * 16 + l15;
#pragma unroll
      for (int n2 = 0; n2 < 4; ++n2) {
        uint2 pk;
        pk.x = cvtpk(o[m][n2][0], o[m][n2][1]);
        pk.y = cvtpk(o[m][n2][2], o[m][n2][3]);
        *reinterpret_cast<uint2*>(&po_[qL * 64 + n2 * 16 + g * 4]) = pk;
      }
      if (g == 0) {
        ml[(size_t)set * 256 + qL * 2] = mrow[m];
        ml[(size_t)set * 256 + qL * 2 + 1] = po[m][0];
      }
    }
  }
}

// ---------------- combine partials (exp2 domain) ----------------
// grid (26, NH): qb = 6 + bx
__global__ __launch_bounds__(256)
void attn_combine(char* __restrict__ partA, char* __restrict__ partB,
                  const float* __restrict__ ml, unsigned short* __restrict__ Y) {
  const int qb = 6 + blockIdx.x;
  const int h = blockIdx.y;
  const int nch = nchunks(qb);
  const int set0 = h * 96 + part_off(qb);
  const int t = threadIdx.x;
  const int r = t >> 1, dh = (t & 1) * 32;

  float mi[6], li[6];
  float M = -1e30f;
  for (int i = 0; i < nch; ++i) {
    mi[i] = ml[(size_t)(set0 + i) * 256 + r * 2];
    li[i] = ml[(size_t)(set0 + i) * 256 + r * 2 + 1];
    M = fmaxf(M, mi[i]);
  }
  float L = 0.f;
  float O[32];
#pragma unroll
  for (int d = 0; d < 32; ++d) O[d] = 0.f;
  for (int i = 0; i < nch; ++i) {
    float w = E2(mi[i] - M);
    L += li[i] * w;
    const unsigned short* po = part_ptr(partA, partB, set0 + i) + r * 64 + dh;
#pragma unroll
    for (int d4 = 0; d4 < 32; d4 += 4) {
      ushort4 v = *reinterpret_cast<const ushort4*>(po + d4);
      O[d4 + 0] += bf2f(v.x) * w;
      O[d4 + 1] += bf2f(v.y) * w;
      O[d4 + 2] += bf2f(v.z) * w;
      O[d4 + 3] += bf2f(v.w) * w;
    }
  }
  float inv = 1.0f / L;
  unsigned short* yp = Y + (size_t)(qb * 128 + r) * C_DIM + h * 64 + dh;
#pragma unroll
  for (int d4 = 0; d4 < 32; d4 += 4) {
    uint2 yk;
    yk.x = cvtpk(O[d4 + 0] * inv, O[d4 + 1] * inv);
    yk.y = cvtpk(O[d4 + 2] * inv, O[d4 + 3] * inv);
    *reinterpret_cast<uint2*>(yp + d4) = yk;
  }
}

// ---------------- launcher ----------------
extern "C" void kernel_launch(void* const* d_in, const int* in_sizes, int n_in,
                              void* d_out, int out_size, void* d_ws, size_t ws_size,
                              hipStream_t stream) {
  const float* x = (const float*)d_in[0];       // [4096][768]
  const float* w_attn = (const float*)d_in[1];  // [768][2304]
  const float* w_proj = (const float*)d_in[2];  // [768][768]
  float* out = (float*)d_out;                   // [4096][768] f32

  char* ws = (char*)d_ws;
  unsigned short* Xb   = (unsigned short*)(ws + 0);          // 6291456 B (dead after QKV -> part spill B)
  unsigned short* WaT  = (unsigned short*)(ws + 6291456);    // 3538944 B (dead after QKV -> ml)
  unsigned short* WpT  = (unsigned short*)(ws + 9830400);    // 1179648 B [768][768]
  unsigned short* Qb   = (unsigned short*)(ws + 11010048);   // 6291456 B [T][768]
  unsigned short* Kb   = (unsigned short*)(ws + 17301504);   // 6291456 B [T][768]
  unsigned short* Vt   = (unsigned short*)(ws + 23592960);   // 6291456 B [768][T]
  unsigned short* Yb   = (unsigned short*)(ws + 29884416);   // 6291456 B [T][768]

  char* partA = (char*)d_out;            // free during attention; overwritten by proj GEMM
  char* partB = (char*)ws;               // Xb region, dead after QKV GEMM
  float* mlp  = (float*)(ws + 6291456);  // WaT region, dead after QKV GEMM

  prep<<<5376, 256, 0, stream>>>(x, Xb, w_attn, WaT, w_proj, WpT);

  gemm_bt<0, 128, 64><<<(T_SEQ / 128) * (2304 / 64), 256, 0, stream>>>(
      Xb, WaT, (void*)Qb, Kb, Vt, T_SEQ, 2304, C_DIM);

  attn_fwd<<<dim3(NH, 102), 256, 0, stream>>>(Qb, Kb, Vt, Yb, partA, partB, mlp);
  attn_combine<<<dim3(26, NH), 256, 0, stream>>>(partA, partB, mlp, Yb);

  gemm_bt<1, 64, 64><<<(T_SEQ / 64) * (C_DIM / 64), 256, 0, stream>>>(
      Yb, WpT, (void*)out, nullptr, nullptr, T_SEQ, C_DIM, C_DIM);
}

// Round 15
// 126.118 us; speedup vs baseline: 1.1161x; 1.0471x over previous
//
#include <hip/hip_runtime.h>

// Causal self-attention: B=1, T=4096, C=768, H=12, hd=64
// f32 in/out, bf16 MFMA compute internally. Flash-decoding s-split.
// R15: gemm0 tile 64x64 (1152->2304 blocks; latency-bound 12-iter loop needs
// TLP, per R12/R7 evidence) + coalesced V^T epilogue via padded LDS transpose
// (was a 64-lane 8KB-stride scatter). attn frozen at R14.

typedef short bf16x8 __attribute__((ext_vector_type(8)));
typedef float f32x4 __attribute__((ext_vector_type(4)));

#define T_SEQ 4096
#define C_DIM 768
#define NH 12
#define HD 64

__device__ __forceinline__ unsigned short f2bf(float f) {
  union { float f; unsigned u; } v; v.f = f;
  unsigned r = v.u + 0x7FFFu + ((v.u >> 16) & 1u);
  return (unsigned short)(r >> 16);
}
__device__ __forceinline__ float bf2f(unsigned short u) {
  union { unsigned u; float f; } v; v.u = ((unsigned)u) << 16;
  return v.f;
}
__device__ __forceinline__ unsigned cvtpk(float a, float b) {
  unsigned r;
  asm("v_cvt_pk_bf16_f32 %0, %1, %2" : "=v"(r) : "v"(a), "v"(b));
  return r;
}
#define E2(x) __builtin_amdgcn_exp2f(x)

#define GLD16(g, l) __builtin_amdgcn_global_load_lds( \
    (const __attribute__((address_space(1))) void*)(g), \
    (__attribute__((address_space(3))) void*)(l), 16, 0, 0)

// ---------------- fused prep: f32->bf16 conv + 2 weight transposes ----------------
__device__ __forceinline__ void tr_body(const float* __restrict__ in,
                                        unsigned short* __restrict__ out,
                                        int R, int Cc, int bx, int by,
                                        float (*tile)[33]) {
  int tx = threadIdx.x & 31, ty = threadIdx.x >> 5;
#pragma unroll
  for (int i = 0; i < 32; i += 8)
    tile[ty + i][tx] = in[(size_t)(by * 32 + ty + i) * Cc + bx * 32 + tx];
  __syncthreads();
#pragma unroll
  for (int i = 0; i < 32; i += 8)
    out[(size_t)(bx * 32 + ty + i) * R + by * 32 + tx] = f2bf(tile[tx][ty + i]);
}

__global__ void prep(const float* __restrict__ x, unsigned short* __restrict__ Xb,
                     const float* __restrict__ w_attn, unsigned short* __restrict__ WaT,
                     const float* __restrict__ w_proj, unsigned short* __restrict__ WpT) {
  __shared__ float tile[32][33];
  const int bid = blockIdx.x;
  if (bid < 3072) {                       // conv x: 4096x768 f32 -> bf16
    int i = (bid * 256 + threadIdx.x) * 4;
    float4 v = *reinterpret_cast<const float4*>(x + i);
    ushort4 o;
    o.x = f2bf(v.x); o.y = f2bf(v.y); o.z = f2bf(v.z); o.w = f2bf(v.w);
    *reinterpret_cast<ushort4*>(Xb + i) = o;
  } else if (bid < 3072 + 1728) {         // w_attn^T: 768x2304 -> [2304][768]
    int b = bid - 3072;
    tr_body(w_attn, WaT, 768, 2304, b % 72, b / 72, tile);
  } else {                                // w_proj^T: 768x768 -> [768][768]
    int b = bid - 4800;
    tr_body(w_proj, WpT, 768, 768, b % 24, b / 24, tile);
  }
}

// ---------------- BT-GEMM: A[M][K] bf16 @ Bt[N][K] bf16 ----------------
// Templated tile; 1-D grid with bijective XCD swizzle.
template <int MODE, int BM, int BN>
__global__ __launch_bounds__(256, 4)
void gemm_bt(const unsigned short* __restrict__ A,
             const unsigned short* __restrict__ Bt,
             void* __restrict__ out0,
             unsigned short* __restrict__ Kout,
             unsigned short* __restrict__ Vt,
             int M, int N, int K) {
  __shared__ __align__(16) unsigned short As[BM * 64];
  __shared__ __align__(16) unsigned short Bs[BN * 64];
  constexpr int AM = BM / 32, AN = BN / 32;   // acc tile counts per wave
  const int nbn = N / BN;
  const int nwg = (M / BM) * nbn;
  const int cpx = nwg >> 3;               // nwg % 8 == 0 (2304, 768)
  const int swz = ((int)blockIdx.x & 7) * cpx + ((int)blockIdx.x >> 3);
  const int bm = swz / nbn, bn = swz % nbn;
  const int tid = threadIdx.x;
  const int wid = tid >> 6, lane = tid & 63;
  const int wr = wid >> 1, wc = wid & 1;
  const int lr = lane & 15;
  const int lk8 = (lane >> 4) * 8;
  const int rsub = lane >> 3, csub = (lane & 7) * 8;

  f32x4 acc[AM][AN] = {};

  const int nk = K / 64;
  for (int kt = 0; kt < nk; ++kt) {
    __syncthreads();
    {
      const unsigned short* gA = A + (size_t)(bm * BM) * K + kt * 64;
      const unsigned short* gB = Bt + (size_t)(bn * BN) * K + kt * 64;
#pragma unroll
      for (int c = 0; c < BM / 32; ++c) {
        int seg = wid * (BM / 32) + c;
        int row = seg * 8 + rsub;
        GLD16(gA + (size_t)row * K + csub, (char*)As + seg * 1024);
      }
#pragma unroll
      for (int c = 0; c < BN / 32; ++c) {
        int seg = wid * (BN / 32) + c;
        int row = seg * 8 + rsub;
        GLD16(gB + (size_t)row * K + csub, (char*)Bs + seg * 1024);
      }
    }
    __syncthreads();
#pragma unroll
    for (int kk = 0; kk < 2; ++kk) {
      bf16x8 a[AM], b[AN];
      int lk = kk * 32 + lk8;
#pragma unroll
      for (int m = 0; m < AM; ++m)
        a[m] = *reinterpret_cast<const bf16x8*>(&As[(wr * (BM / 2) + m * 16 + lr) * 64 + lk]);
#pragma unroll
      for (int n = 0; n < AN; ++n)
        b[n] = *reinterpret_cast<const bf16x8*>(&Bs[(wc * (BN / 2) + n * 16 + lr) * 64 + lk]);
#pragma unroll
      for (int m = 0; m < AM; ++m)
#pragma unroll
        for (int n = 0; n < AN; ++n)
          acc[m][n] = __builtin_amdgcn_mfma_f32_16x16x32_bf16(a[m], b[n], acc[m][n], 0, 0, 0);
    }
  }

  const int row0 = bm * BM + wr * (BM / 2);
  const int col0 = bn * BN + wc * (BN / 2);
  const int g = lane >> 4;

  if constexpr (MODE == 0) {
    if (bn * BN >= 1536) {
      // V block: coalesced V^T store via padded LDS transpose.
      __shared__ unsigned short Vst[64][72];  // stride 144B: 16B-aligned rows
      const int dl0 = wc * (BN / 2);
      const int tl0 = wr * (BM / 2);
#pragma unroll
      for (int m = 0; m < AM; ++m)
#pragma unroll
        for (int n = 0; n < AN; ++n) {
          uint2 pk;
          pk.x = cvtpk(acc[m][n][0], acc[m][n][1]);
          pk.y = cvtpk(acc[m][n][2], acc[m][n][3]);
          *reinterpret_cast<uint2*>(&Vst[dl0 + n * 16 + lr][tl0 + m * 16 + g * 4]) = pk;
        }
      __syncthreads();
      const int dl = tid >> 2;
      const int tb = (tid & 3) * 16;
      uint4 a0 = *reinterpret_cast<const uint4*>(&Vst[dl][tb]);
      uint4 a1 = *reinterpret_cast<const uint4*>(&Vst[dl][tb + 8]);
      unsigned short* dst = Vt + (size_t)(bn * BN - 1536 + dl) * M + bm * BM + tb;
      *reinterpret_cast<uint4*>(dst) = a0;
      *reinterpret_cast<uint4*>(dst + 8) = a1;
      return;
    }
  }

#pragma unroll
  for (int m = 0; m < AM; ++m)
#pragma unroll
    for (int n = 0; n < AN; ++n)
#pragma unroll
      for (int j = 0; j < 4; ++j) {
        int r = row0 + m * 16 + g * 4 + j;
        int c = col0 + n * 16 + lr;
        float v = acc[m][n][j];
        if (MODE == 0) {
          if (c < 768)  // Q pre-scaled by (1/8)*log2(e) for exp2-domain softmax
            ((unsigned short*)out0)[(size_t)r * 768 + c] = f2bf(v * 0.180336884f);
          else
            Kout[(size_t)r * 768 + (c - 768)] = f2bf(v);
        } else {
          ((float*)out0)[(size_t)r * N + c] = v;
        }
      }
}

// ---------------- attention helpers ----------------
__device__ __forceinline__ void stage_k(const unsigned short* __restrict__ Kb,
                                        unsigned short* Kbuf,
                                        int h, int st, int wid, int lane) {
  const int cg = lane & 7, rsub = (lane >> 3) & 7;
  const unsigned short* gK = Kb + (size_t)(st * 64) * C_DIM + h * 64;
#pragma unroll
  for (int c = 0; c < 2; ++c) {
    int seg = wid * 2 + c;
    int row = seg * 8 + rsub;
    GLD16(gK + (size_t)row * C_DIM + (cg ^ rsub) * 8, (char*)Kbuf + seg * 1024);
  }
}
__device__ __forceinline__ void stage_v(const unsigned short* __restrict__ Vt,
                                        unsigned short* Vbuf,
                                        int h, int st, int wid, int lane) {
  const int cg = lane & 7, rsub = (lane >> 3) & 7;
  const unsigned short* gV = Vt + (size_t)(h * 64) * T_SEQ + st * 64;
#pragma unroll
  for (int c = 0; c < 2; ++c) {
    int seg = wid * 2 + c;
    int row = seg * 8 + rsub;
    GLD16(gV + (size_t)row * T_SEQ + (cg ^ rsub) * 8, (char*)Vbuf + seg * 1024);
  }
}

// chunk size 12 tiles; nst_total = 2qb+2; nch = ceil((2qb+2)/12)
__device__ __forceinline__ int nchunks(int q) { return (2 * q + 13) / 12; }
// partial sets for qb>=6 (nch>=2): 96 sets/head
__device__ __forceinline__ int part_off(int qb) {
  if (qb < 12) return (qb - 6) * 2;
  if (qb < 18) return 12 + (qb - 12) * 3;
  if (qb < 24) return 30 + (qb - 18) * 4;
  if (qb < 30) return 54 + (qb - 24) * 5;
  return 84 + (qb - 30) * 6;
}
// 1152 sets x 16KB: 768 in d_out, 384 in Xb region
__device__ __forceinline__ unsigned short* part_ptr(char* pA, char* pB, int set) {
  return (set < 768) ? (unsigned short*)(pA + (size_t)set * 16384)
                     : (unsigned short*)(pB + (size_t)(set - 768) * 16384);
}

// ---------------- flash attention (causal, swapped QK^T, s-chunked) ----------------
// grid = (NH, 102): x = head (fastest dispatch dim) -> LPT across heads.
// K double-buffered, V single-buffered (staged after end barrier): LDS 40KB.
__global__ __launch_bounds__(256, 3)
void attn_fwd(const unsigned short* __restrict__ Qb,
              const unsigned short* __restrict__ Kb,
              const unsigned short* __restrict__ Vt,
              unsigned short* __restrict__ Y,
              char* __restrict__ partA, char* __restrict__ partB,
              float* __restrict__ ml) {
  __shared__ __align__(16) unsigned short Ks[2][64 * 64];
  __shared__ __align__(16) unsigned short Vs[64 * 64];  // [d][s], single buffer
  __shared__ __align__(16) unsigned short Ps[4][32 * 64];

  const int h = blockIdx.x;
  int qb = 0, ck = 0;
  {
    int idx = blockIdx.y;
    for (int q = 31; q >= 0; --q) {
      int nc = nchunks(q);
      if (idx < nc) { qb = q; ck = idx; break; }
      idx -= nc;
    }
  }
  const int nch = nchunks(qb);
  const int q0 = qb * 128;
  const int nst_total = 2 * qb + 2;
  const int st0 = ck * 12;
  const int st1 = (st0 + 12 < nst_total) ? st0 + 12 : nst_total;

  const int tid = threadIdx.x;
  const int wid = tid >> 6, lane = tid & 63;
  const int l15 = lane & 15, g = lane >> 4;
  const int sw = l15 & 7;
  const int qw = q0 + wid * 32;

  bf16x8 qf[2][2];
#pragma unroll
  for (int m = 0; m < 2; ++m)
#pragma unroll
    for (int kk = 0; kk < 2; ++kk)
      qf[m][kk] = *reinterpret_cast<const bf16x8*>(
          &Qb[(size_t)(qw + m * 16 + l15) * C_DIM + h * 64 + kk * 32 + g * 8]);

  // all-ones bf16 A-fragment for the denominator MFMA (bf16 1.0 = 0x3F80)
  bf16x8 ones;
#pragma unroll
  for (int e = 0; e < 8; ++e) ones[e] = (short)0x3F80;

  f32x4 o[2][4] = {};  // O^T fragments: row=d, col=q
  f32x4 po[2] = {};    // denominator accumulator: every reg = sum_s P[q][s]
  float mrow[2] = {-1e30f, -1e30f};

  stage_k(Kb, Ks[0], h, st0, wid, lane);
  stage_v(Vt, Vs, h, st0, wid, lane);
  int cur = 0;

  for (int st = st0; st < st1; ++st) {
    const bool haveNext = (st + 1 < st1);
    if (haveNext) {
      stage_k(Kb, Ks[cur ^ 1], h, st + 1, wid, lane);
      // queue: [K(t):2, V(t):2, K(t+1):2] -> wait K(t),V(t); K(t+1) in flight
      asm volatile("s_waitcnt vmcnt(2)" ::: "memory");
    } else {
      asm volatile("s_waitcnt vmcnt(0)" ::: "memory");
    }
    __builtin_amdgcn_s_barrier();

    const bool active = (st * 64) <= (qw + 31);
    if (active) {
      const unsigned short* K_ = Ks[cur];

      // S^T = K @ Q^T  (S in log2 domain: Q pre-scaled by 0.125*log2e)
      f32x4 sT[2][4] = {};
      __builtin_amdgcn_s_setprio(1);
#pragma unroll
      for (int kk = 0; kk < 2; ++kk) {
        bf16x8 kf[4];
#pragma unroll
        for (int n = 0; n < 4; ++n)
          kf[n] = *reinterpret_cast<const bf16x8*>(
              &K_[(n * 16 + l15) * 64 + (((kk * 4 + g) ^ sw) * 8)]);
#pragma unroll
        for (int m = 0; m < 2; ++m)
#pragma unroll
          for (int n = 0; n < 4; ++n)
            sT[m][n] = __builtin_amdgcn_mfma_f32_16x16x32_bf16(kf[n], qf[m][kk], sT[m][n], 0, 0, 0);
      }
      __builtin_amdgcn_s_setprio(0);

      unsigned short* Pw = Ps[wid];
#pragma unroll
      for (int m = 0; m < 2; ++m) {
        if (!(st * 64 + 63 <= qw + m * 16)) {
          // diagonal tile: apply causal mask (rare, wave-uniform branch)
          const int bound = (qw + m * 16 + l15) - st * 64;
#pragma unroll
          for (int n = 0; n < 4; ++n)
#pragma unroll
            for (int jj = 0; jj < 4; ++jj) {
              int sl = n * 16 + g * 4 + jj;
              if (sl > bound) sT[m][n][jj] = -1e30f;
            }
        }
        // tree max
        float vm[4];
#pragma unroll
        for (int n = 0; n < 4; ++n)
          vm[n] = fmaxf(fmaxf(sT[m][n][0], sT[m][n][1]), fmaxf(sT[m][n][2], sT[m][n][3]));
        float vmax = fmaxf(fmaxf(vm[0], vm[1]), fmaxf(vm[2], vm[3]));
        vmax = fmaxf(vmax, __shfl_xor(vmax, 16, 64));
        vmax = fmaxf(vmax, __shfl_xor(vmax, 32, 64));
        // defer-rescale (T13): keep old max while growth <= 8 (P bounded by 2^8)
        const bool defer = (__all(vmax <= mrow[m] + 8.0f) != 0);
        const float mnew = defer ? mrow[m] : fmaxf(mrow[m], vmax);
#pragma unroll
        for (int n = 0; n < 4; ++n)
#pragma unroll
          for (int jj = 0; jj < 4; ++jj)
            sT[m][n][jj] = E2(sT[m][n][jj] - mnew);
        if (!defer) {
          float alpha = E2(mrow[m] - mnew);
          mrow[m] = mnew;
#pragma unroll
          for (int n2 = 0; n2 < 4; ++n2) o[m][n2] *= alpha;
          po[m] *= alpha;
        }
#pragma unroll
        for (int n = 0; n < 4; ++n) {
          uint2 pw;
          pw.x = cvtpk(sT[m][n][0], sT[m][n][1]);
          pw.y = cvtpk(sT[m][n][2], sT[m][n][3]);
          *reinterpret_cast<uint2*>(
              &Pw[(m * 16 + l15) * 64 + (((n * 2 + (g >> 1)) ^ sw) * 8) + (g & 1) * 4]) = pw;
        }
      }
      asm volatile("s_waitcnt lgkmcnt(0)" ::: "memory");

      // O^T += V^T @ P^T ; denominator += ones @ P^T (matrix-pipe row-sum)
      __builtin_amdgcn_s_setprio(1);
#pragma unroll
      for (int ks = 0; ks < 2; ++ks) {
        bf16x8 vf[4], pf[2];
#pragma unroll
        for (int n2 = 0; n2 < 4; ++n2)
          vf[n2] = *reinterpret_cast<const bf16x8*>(
              &Vs[(n2 * 16 + l15) * 64 + (((ks * 4 + g) ^ sw) * 8)]);
#pragma unroll
        for (int m = 0; m < 2; ++m)
          pf[m] = *reinterpret_cast<const bf16x8*>(
              &Pw[(m * 16 + l15) * 64 + (((ks * 4 + g) ^ sw) * 8)]);
#pragma unroll
        for (int m = 0; m < 2; ++m) {
#pragma unroll
          for (int n2 = 0; n2 < 4; ++n2)
            o[m][n2] = __builtin_amdgcn_mfma_f32_16x16x32_bf16(vf[n2], pf[m], o[m][n2], 0, 0, 0);
          po[m] = __builtin_amdgcn_mfma_f32_16x16x32_bf16(ones, pf[m], po[m], 0, 0, 0);
        }
      }
      __builtin_amdgcn_s_setprio(0);
    }
    asm volatile("" ::: "memory");
    __builtin_amdgcn_s_barrier();
    // V(t+1) staged only after ALL waves passed the barrier (done reading Vs)
    if (haveNext) stage_v(Vt, Vs, h, st + 1, wid, lane);
    cur ^= 1;
  }

  if (nch == 1) {
#pragma unroll
    for (int m = 0; m < 2; ++m) {
      float inv = 1.0f / po[m][0];
      int qg = qw + m * 16 + l15;
#pragma unroll
      for (int n2 = 0; n2 < 4; ++n2) {
        uint2 yk;
        yk.x = cvtpk(o[m][n2][0] * inv, o[m][n2][1] * inv);
        yk.y = cvtpk(o[m][n2][2] * inv, o[m][n2][3] * inv);
        *reinterpret_cast<uint2*>(&Y[(size_t)qg * C_DIM + h * 64 + n2 * 16 + g * 4]) = yk;
      }
    }
  } else {
    const int set = h * 96 + part_off(qb) + ck;
    unsigned short* po_ = part_ptr(partA, partB, set);
#pragma unroll
    for (int m = 0; m < 2; ++m) {
      int qL = wid * 32 + m * 16 + l15;
#pragma unroll
      for (int n2 = 0; n2 < 4; ++n2) {
        uint2 pk;
        pk.x = cvtpk(o[m][n2][0], o[m][n2][1]);
        pk.y = cvtpk(o[m][n2][2], o[m][n2][3]);
        *reinterpret_cast<uint2*>(&po_[qL * 64 + n2 * 16 + g * 4]) = pk;
      }
      if (g == 0) {
        ml[(size_t)set * 256 + qL * 2] = mrow[m];
        ml[(size_t)set * 256 + qL * 2 + 1] = po[m][0];
      }
    }
  }
}

// ---------------- combine partials (exp2 domain) ----------------
// grid (26, NH): qb = 6 + bx
__global__ __launch_bounds__(256)
void attn_combine(char* __restrict__ partA, char* __restrict__ partB,
                  const float* __restrict__ ml, unsigned short* __restrict__ Y) {
  const int qb = 6 + blockIdx.x;
  const int h = blockIdx.y;
  const int nch = nchunks(qb);
  const int set0 = h * 96 + part_off(qb);
  const int t = threadIdx.x;
  const int r = t >> 1, dh = (t & 1) * 32;

  float mi[6], li[6];
  float M = -1e30f;
  for (int i = 0; i < nch; ++i) {
    mi[i] = ml[(size_t)(set0 + i) * 256 + r * 2];
    li[i] = ml[(size_t)(set0 + i) * 256 + r * 2 + 1];
    M = fmaxf(M, mi[i]);
  }
  float L = 0.f;
  float O[32];
#pragma unroll
  for (int d = 0; d < 32; ++d) O[d] = 0.f;
  for (int i = 0; i < nch; ++i) {
    float w = E2(mi[i] - M);
    L += li[i] * w;
    const unsigned short* po = part_ptr(partA, partB, set0 + i) + r * 64 + dh;
#pragma unroll
    for (int d4 = 0; d4 < 32; d4 += 4) {
      ushort4 v = *reinterpret_cast<const ushort4*>(po + d4);
      O[d4 + 0] += bf2f(v.x) * w;
      O[d4 + 1] += bf2f(v.y) * w;
      O[d4 + 2] += bf2f(v.z) * w;
      O[d4 + 3] += bf2f(v.w) * w;
    }
  }
  float inv = 1.0f / L;
  unsigned short* yp = Y + (size_t)(qb * 128 + r) * C_DIM + h * 64 + dh;
#pragma unroll
  for (int d4 = 0; d4 < 32; d4 += 4) {
    uint2 yk;
    yk.x = cvtpk(O[d4 + 0] * inv, O[d4 + 1] * inv);
    yk.y = cvtpk(O[d4 + 2] * inv, O[d4 + 3] * inv);
    *reinterpret_cast<uint2*>(yp + d4) = yk;
  }
}

// ---------------- launcher ----------------
extern "C" void kernel_launch(void* const* d_in, const int* in_sizes, int n_in,
                              void* d_out, int out_size, void* d_ws, size_t ws_size,
                              hipStream_t stream) {
  const float* x = (const float*)d_in[0];       // [4096][768]
  const float* w_attn = (const float*)d_in[1];  // [768][2304]
  const float* w_proj = (const float*)d_in[2];  // [768][768]
  float* out = (float*)d_out;                   // [4096][768] f32

  char* ws = (char*)d_ws;
  unsigned short* Xb   = (unsigned short*)(ws + 0);          // 6291456 B (dead after QKV -> part spill B)
  unsigned short* WaT  = (unsigned short*)(ws + 6291456);    // 3538944 B (dead after QKV -> ml)
  unsigned short* WpT  = (unsigned short*)(ws + 9830400);    // 1179648 B [768][768]
  unsigned short* Qb   = (unsigned short*)(ws + 11010048);   // 6291456 B [T][768]
  unsigned short* Kb   = (unsigned short*)(ws + 17301504);   // 6291456 B [T][768]
  unsigned short* Vt   = (unsigned short*)(ws + 23592960);   // 6291456 B [768][T]
  unsigned short* Yb   = (unsigned short*)(ws + 29884416);   // 6291456 B [T][768]

  char* partA = (char*)d_out;            // free during attention; overwritten by proj GEMM
  char* partB = (char*)ws;               // Xb region, dead after QKV GEMM
  float* mlp  = (float*)(ws + 6291456);  // WaT region, dead after QKV GEMM

  prep<<<5376, 256, 0, stream>>>(x, Xb, w_attn, WaT, w_proj, WpT);

  gemm_bt<0, 64, 64><<<(T_SEQ / 64) * (2304 / 64), 256, 0, stream>>>(
      Xb, WaT, (void*)Qb, Kb, Vt, T_SEQ, 2304, C_DIM);

  attn_fwd<<<dim3(NH, 102), 256, 0, stream>>>(Qb, Kb, Vt, Yb, partA, partB, mlp);
  attn_combine<<<dim3(26, NH), 256, 0, stream>>>(partA, partB, mlp, Yb);

  gemm_bt<1, 64, 64><<<(T_SEQ / 64) * (C_DIM / 64), 256, 0, stream>>>(
      Yb, WpT, (void*)out, nullptr, nullptr, T_SEQ, C_DIM, C_DIM);
}

// Round 16
// 120.204 us; speedup vs baseline: 1.1710x; 1.0492x over previous
//
#include <hip/hip_runtime.h>

// Causal self-attention: B=1, T=4096, C=768, H=12, hd=64
// f32 in/out, bf16 MFMA compute internally. Flash-decoding s-split.
// R16: GEMM double-buffered staging with counted vmcnt at 64x64 tile (dbuf
// LDS 32KB keeps 4 blocks/CU -- R7's dbuf regression was the 64KB occupancy
// cliff, absent here). V^T epilogue LDS overlaid on staging buffers.
// attn frozen at R14/R15.

typedef short bf16x8 __attribute__((ext_vector_type(8)));
typedef float f32x4 __attribute__((ext_vector_type(4)));

#define T_SEQ 4096
#define C_DIM 768
#define NH 12
#define HD 64

__device__ __forceinline__ unsigned short f2bf(float f) {
  union { float f; unsigned u; } v; v.f = f;
  unsigned r = v.u + 0x7FFFu + ((v.u >> 16) & 1u);
  return (unsigned short)(r >> 16);
}
__device__ __forceinline__ float bf2f(unsigned short u) {
  union { unsigned u; float f; } v; v.u = ((unsigned)u) << 16;
  return v.f;
}
__device__ __forceinline__ unsigned cvtpk(float a, float b) {
  unsigned r;
  asm("v_cvt_pk_bf16_f32 %0, %1, %2" : "=v"(r) : "v"(a), "v"(b));
  return r;
}
#define E2(x) __builtin_amdgcn_exp2f(x)

#define GLD16(g, l) __builtin_amdgcn_global_load_lds( \
    (const __attribute__((address_space(1))) void*)(g), \
    (__attribute__((address_space(3))) void*)(l), 16, 0, 0)

// ---------------- fused prep: f32->bf16 conv + 2 weight transposes ----------------
__device__ __forceinline__ void tr_body(const float* __restrict__ in,
                                        unsigned short* __restrict__ out,
                                        int R, int Cc, int bx, int by,
                                        float (*tile)[33]) {
  int tx = threadIdx.x & 31, ty = threadIdx.x >> 5;
#pragma unroll
  for (int i = 0; i < 32; i += 8)
    tile[ty + i][tx] = in[(size_t)(by * 32 + ty + i) * Cc + bx * 32 + tx];
  __syncthreads();
#pragma unroll
  for (int i = 0; i < 32; i += 8)
    out[(size_t)(bx * 32 + ty + i) * R + by * 32 + tx] = f2bf(tile[tx][ty + i]);
}

__global__ void prep(const float* __restrict__ x, unsigned short* __restrict__ Xb,
                     const float* __restrict__ w_attn, unsigned short* __restrict__ WaT,
                     const float* __restrict__ w_proj, unsigned short* __restrict__ WpT) {
  __shared__ float tile[32][33];
  const int bid = blockIdx.x;
  if (bid < 3072) {                       // conv x: 4096x768 f32 -> bf16
    int i = (bid * 256 + threadIdx.x) * 4;
    float4 v = *reinterpret_cast<const float4*>(x + i);
    ushort4 o;
    o.x = f2bf(v.x); o.y = f2bf(v.y); o.z = f2bf(v.z); o.w = f2bf(v.w);
    *reinterpret_cast<ushort4*>(Xb + i) = o;
  } else if (bid < 3072 + 1728) {         // w_attn^T: 768x2304 -> [2304][768]
    int b = bid - 3072;
    tr_body(w_attn, WaT, 768, 2304, b % 72, b / 72, tile);
  } else {                                // w_proj^T: 768x768 -> [768][768]
    int b = bid - 4800;
    tr_body(w_proj, WpT, 768, 768, b % 24, b / 24, tile);
  }
}

// ---------------- BT-GEMM: A[M][K] bf16 @ Bt[N][K] bf16 ----------------
// Double-buffered LDS, counted vmcnt (loads stay in flight across barriers),
// 1-D grid with bijective XCD swizzle.
template <int MODE, int BM, int BN>
__global__ __launch_bounds__(256, 4)
void gemm_bt(const unsigned short* __restrict__ A,
             const unsigned short* __restrict__ Bt,
             void* __restrict__ out0,
             unsigned short* __restrict__ Kout,
             unsigned short* __restrict__ Vt,
             int M, int N, int K) {
  __shared__ __align__(16) unsigned short smem[2 * (BM + BN) * 64];
  constexpr int AM = BM / 32, AN = BN / 32;   // acc tile counts per wave
  const int nbn = N / BN;
  const int nwg = (M / BM) * nbn;
  const int cpx = nwg >> 3;               // nwg % 8 == 0 (2304, 768)
  const int swz = ((int)blockIdx.x & 7) * cpx + ((int)blockIdx.x >> 3);
  const int bm = swz / nbn, bn = swz % nbn;
  const int tid = threadIdx.x;
  const int wid = tid >> 6, lane = tid & 63;
  const int wr = wid >> 1, wc = wid & 1;
  const int lr = lane & 15;
  const int lk8 = (lane >> 4) * 8;
  const int rsub = lane >> 3, csub = (lane & 7) * 8;

  auto Abuf = [&](int b) { return smem + b * BM * 64; };
  auto Bbuf = [&](int b) { return smem + 2 * BM * 64 + b * BN * 64; };

  f32x4 acc[AM][AN] = {};
  const int nk = K / 64;

  auto STAGE = [&](int kt, int buf) {
    const unsigned short* gA = A + (size_t)(bm * BM) * K + kt * 64;
    const unsigned short* gB = Bt + (size_t)(bn * BN) * K + kt * 64;
#pragma unroll
    for (int c = 0; c < BM / 32; ++c) {
      int seg = wid * (BM / 32) + c;
      int row = seg * 8 + rsub;
      GLD16(gA + (size_t)row * K + csub, (char*)Abuf(buf) + seg * 1024);
    }
#pragma unroll
    for (int c = 0; c < BN / 32; ++c) {
      int seg = wid * (BN / 32) + c;
      int row = seg * 8 + rsub;
      GLD16(gB + (size_t)row * K + csub, (char*)Bbuf(buf) + seg * 1024);
    }
  };

  STAGE(0, 0);
  int cur = 0;
  for (int kt = 0; kt < nk; ++kt) {
    if (kt + 1 < nk) {
      STAGE(kt + 1, cur ^ 1);
      constexpr int LOADS = BM / 32 + BN / 32;  // per-wave loads per stage
      if constexpr (LOADS == 4)
        asm volatile("s_waitcnt vmcnt(4)" ::: "memory");
      else if constexpr (LOADS == 6)
        asm volatile("s_waitcnt vmcnt(6)" ::: "memory");
      else
        asm volatile("s_waitcnt vmcnt(0)" ::: "memory");
    } else {
      asm volatile("s_waitcnt vmcnt(0)" ::: "memory");
    }
    __builtin_amdgcn_s_barrier();

    const unsigned short* As = Abuf(cur);
    const unsigned short* Bs = Bbuf(cur);
#pragma unroll
    for (int kk = 0; kk < 2; ++kk) {
      bf16x8 a[AM], b[AN];
      int lk = kk * 32 + lk8;
#pragma unroll
      for (int m = 0; m < AM; ++m)
        a[m] = *reinterpret_cast<const bf16x8*>(&As[(wr * (BM / 2) + m * 16 + lr) * 64 + lk]);
#pragma unroll
      for (int n = 0; n < AN; ++n)
        b[n] = *reinterpret_cast<const bf16x8*>(&Bs[(wc * (BN / 2) + n * 16 + lr) * 64 + lk]);
#pragma unroll
      for (int m = 0; m < AM; ++m)
#pragma unroll
        for (int n = 0; n < AN; ++n)
          acc[m][n] = __builtin_amdgcn_mfma_f32_16x16x32_bf16(a[m], b[n], acc[m][n], 0, 0, 0);
    }
    asm volatile("" ::: "memory");
    __builtin_amdgcn_s_barrier();  // all waves done reading buf[cur] before re-stage
    cur ^= 1;
  }

  const int row0 = bm * BM + wr * (BM / 2);
  const int col0 = bn * BN + wc * (BN / 2);
  const int g = lane >> 4;

  if constexpr (MODE == 0) {
    if (bn * BN >= 1536) {
      // V block: coalesced V^T store via padded LDS transpose.
      // Overlay the (now dead) staging buffers: need 64*72 shorts <= smem.
      __syncthreads();
      unsigned short (*Vst)[72] = reinterpret_cast<unsigned short (*)[72]>(smem);
      const int dl0 = wc * (BN / 2);
      const int tl0 = wr * (BM / 2);
#pragma unroll
      for (int m = 0; m < AM; ++m)
#pragma unroll
        for (int n = 0; n < AN; ++n) {
          uint2 pk;
          pk.x = cvtpk(acc[m][n][0], acc[m][n][1]);
          pk.y = cvtpk(acc[m][n][2], acc[m][n][3]);
          *reinterpret_cast<uint2*>(&Vst[dl0 + n * 16 + lr][tl0 + m * 16 + g * 4]) = pk;
        }
      __syncthreads();
      const int dl = tid >> 2;
      const int tb = (tid & 3) * 16;
      uint4 a0 = *reinterpret_cast<const uint4*>(&Vst[dl][tb]);
      uint4 a1 = *reinterpret_cast<const uint4*>(&Vst[dl][tb + 8]);
      unsigned short* dst = Vt + (size_t)(bn * BN - 1536 + dl) * M + bm * BM + tb;
      *reinterpret_cast<uint4*>(dst) = a0;
      *reinterpret_cast<uint4*>(dst + 8) = a1;
      return;
    }
  }

#pragma unroll
  for (int m = 0; m < AM; ++m)
#pragma unroll
    for (int n = 0; n < AN; ++n)
#pragma unroll
      for (int j = 0; j < 4; ++j) {
        int r = row0 + m * 16 + g * 4 + j;
        int c = col0 + n * 16 + lr;
        float v = acc[m][n][j];
        if (MODE == 0) {
          if (c < 768)  // Q pre-scaled by (1/8)*log2(e) for exp2-domain softmax
            ((unsigned short*)out0)[(size_t)r * 768 + c] = f2bf(v * 0.180336884f);
          else
            Kout[(size_t)r * 768 + (c - 768)] = f2bf(v);
        } else {
          ((float*)out0)[(size_t)r * N + c] = v;
        }
      }
}

// ---------------- attention helpers ----------------
__device__ __forceinline__ void stage_k(const unsigned short* __restrict__ Kb,
                                        unsigned short* Kbuf,
                                        int h, int st, int wid, int lane) {
  const int cg = lane & 7, rsub = (lane >> 3) & 7;
  const unsigned short* gK = Kb + (size_t)(st * 64) * C_DIM + h * 64;
#pragma unroll
  for (int c = 0; c < 2; ++c) {
    int seg = wid * 2 + c;
    int row = seg * 8 + rsub;
    GLD16(gK + (size_t)row * C_DIM + (cg ^ rsub) * 8, (char*)Kbuf + seg * 1024);
  }
}
__device__ __forceinline__ void stage_v(const unsigned short* __restrict__ Vt,
                                        unsigned short* Vbuf,
                                        int h, int st, int wid, int lane) {
  const int cg = lane & 7, rsub = (lane >> 3) & 7;
  const unsigned short* gV = Vt + (size_t)(h * 64) * T_SEQ + st * 64;
#pragma unroll
  for (int c = 0; c < 2; ++c) {
    int seg = wid * 2 + c;
    int row = seg * 8 + rsub;
    GLD16(gV + (size_t)row * T_SEQ + (cg ^ rsub) * 8, (char*)Vbuf + seg * 1024);
  }
}

// chunk size 12 tiles; nst_total = 2qb+2; nch = ceil((2qb+2)/12)
__device__ __forceinline__ int nchunks(int q) { return (2 * q + 13) / 12; }
// partial sets for qb>=6 (nch>=2): 96 sets/head
__device__ __forceinline__ int part_off(int qb) {
  if (qb < 12) return (qb - 6) * 2;
  if (qb < 18) return 12 + (qb - 12) * 3;
  if (qb < 24) return 30 + (qb - 18) * 4;
  if (qb < 30) return 54 + (qb - 24) * 5;
  return 84 + (qb - 30) * 6;
}
// 1152 sets x 16KB: 768 in d_out, 384 in Xb region
__device__ __forceinline__ unsigned short* part_ptr(char* pA, char* pB, int set) {
  return (set < 768) ? (unsigned short*)(pA + (size_t)set * 16384)
                     : (unsigned short*)(pB + (size_t)(set - 768) * 16384);
}

// ---------------- flash attention (causal, swapped QK^T, s-chunked) ----------------
// grid = (NH, 102): x = head (fastest dispatch dim) -> LPT across heads.
// K double-buffered, V single-buffered (staged after end barrier): LDS 40KB.
__global__ __launch_bounds__(256, 3)
void attn_fwd(const unsigned short* __restrict__ Qb,
              const unsigned short* __restrict__ Kb,
              const unsigned short* __restrict__ Vt,
              unsigned short* __restrict__ Y,
              char* __restrict__ partA, char* __restrict__ partB,
              float* __restrict__ ml) {
  __shared__ __align__(16) unsigned short Ks[2][64 * 64];
  __shared__ __align__(16) unsigned short Vs[64 * 64];  // [d][s], single buffer
  __shared__ __align__(16) unsigned short Ps[4][32 * 64];

  const int h = blockIdx.x;
  int qb = 0, ck = 0;
  {
    int idx = blockIdx.y;
    for (int q = 31; q >= 0; --q) {
      int nc = nchunks(q);
      if (idx < nc) { qb = q; ck = idx; break; }
      idx -= nc;
    }
  }
  const int nch = nchunks(qb);
  const int q0 = qb * 128;
  const int nst_total = 2 * qb + 2;
  const int st0 = ck * 12;
  const int st1 = (st0 + 12 < nst_total) ? st0 + 12 : nst_total;

  const int tid = threadIdx.x;
  const int wid = tid >> 6, lane = tid & 63;
  const int l15 = lane & 15, g = lane >> 4;
  const int sw = l15 & 7;
  const int qw = q0 + wid * 32;

  bf16x8 qf[2][2];
#pragma unroll
  for (int m = 0; m < 2; ++m)
#pragma unroll
    for (int kk = 0; kk < 2; ++kk)
      qf[m][kk] = *reinterpret_cast<const bf16x8*>(
          &Qb[(size_t)(qw + m * 16 + l15) * C_DIM + h * 64 + kk * 32 + g * 8]);

  // all-ones bf16 A-fragment for the denominator MFMA (bf16 1.0 = 0x3F80)
  bf16x8 ones;
#pragma unroll
  for (int e = 0; e < 8; ++e) ones[e] = (short)0x3F80;

  f32x4 o[2][4] = {};  // O^T fragments: row=d, col=q
  f32x4 po[2] = {};    // denominator accumulator: every reg = sum_s P[q][s]
  float mrow[2] = {-1e30f, -1e30f};

  stage_k(Kb, Ks[0], h, st0, wid, lane);
  stage_v(Vt, Vs, h, st0, wid, lane);
  int cur = 0;

  for (int st = st0; st < st1; ++st) {
    const bool haveNext = (st + 1 < st1);
    if (haveNext) {
      stage_k(Kb, Ks[cur ^ 1], h, st + 1, wid, lane);
      // queue: [K(t):2, V(t):2, K(t+1):2] -> wait K(t),V(t); K(t+1) in flight
      asm volatile("s_waitcnt vmcnt(2)" ::: "memory");
    } else {
      asm volatile("s_waitcnt vmcnt(0)" ::: "memory");
    }
    __builtin_amdgcn_s_barrier();

    const bool active = (st * 64) <= (qw + 31);
    if (active) {
      const unsigned short* K_ = Ks[cur];

      // S^T = K @ Q^T  (S in log2 domain: Q pre-scaled by 0.125*log2e)
      f32x4 sT[2][4] = {};
      __builtin_amdgcn_s_setprio(1);
#pragma unroll
      for (int kk = 0; kk < 2; ++kk) {
        bf16x8 kf[4];
#pragma unroll
        for (int n = 0; n < 4; ++n)
          kf[n] = *reinterpret_cast<const bf16x8*>(
              &K_[(n * 16 + l15) * 64 + (((kk * 4 + g) ^ sw) * 8)]);
#pragma unroll
        for (int m = 0; m < 2; ++m)
#pragma unroll
          for (int n = 0; n < 4; ++n)
            sT[m][n] = __builtin_amdgcn_mfma_f32_16x16x32_bf16(kf[n], qf[m][kk], sT[m][n], 0, 0, 0);
      }
      __builtin_amdgcn_s_setprio(0);

      unsigned short* Pw = Ps[wid];
#pragma unroll
      for (int m = 0; m < 2; ++m) {
        if (!(st * 64 + 63 <= qw + m * 16)) {
          // diagonal tile: apply causal mask (rare, wave-uniform branch)
          const int bound = (qw + m * 16 + l15) - st * 64;
#pragma unroll
          for (int n = 0; n < 4; ++n)
#pragma unroll
            for (int jj = 0; jj < 4; ++jj) {
              int sl = n * 16 + g * 4 + jj;
              if (sl > bound) sT[m][n][jj] = -1e30f;
            }
        }
        // tree max
        float vm[4];
#pragma unroll
        for (int n = 0; n < 4; ++n)
          vm[n] = fmaxf(fmaxf(sT[m][n][0], sT[m][n][1]), fmaxf(sT[m][n][2], sT[m][n][3]));
        float vmax = fmaxf(fmaxf(vm[0], vm[1]), fmaxf(vm[2], vm[3]));
        vmax = fmaxf(vmax, __shfl_xor(vmax, 16, 64));
        vmax = fmaxf(vmax, __shfl_xor(vmax, 32, 64));
        // defer-rescale (T13): keep old max while growth <= 8 (P bounded by 2^8)
        const bool defer = (__all(vmax <= mrow[m] + 8.0f) != 0);
        const float mnew = defer ? mrow[m] : fmaxf(mrow[m], vmax);
#pragma unroll
        for (int n = 0; n < 4; ++n)
#pragma unroll
          for (int jj = 0; jj < 4; ++jj)
            sT[m][n][jj] = E2(sT[m][n][jj] - mnew);
        if (!defer) {
          float alpha = E2(mrow[m] - mnew);
          mrow[m] = mnew;
#pragma unroll
          for (int n2 = 0; n2 < 4; ++n2) o[m][n2] *= alpha;
          po[m] *= alpha;
        }
#pragma unroll
        for (int n = 0; n < 4; ++n) {
          uint2 pw;
          pw.x = cvtpk(sT[m][n][0], sT[m][n][1]);
          pw.y = cvtpk(sT[m][n][2], sT[m][n][3]);
          *reinterpret_cast<uint2*>(
              &Pw[(m * 16 + l15) * 64 + (((n * 2 + (g >> 1)) ^ sw) * 8) + (g & 1) * 4]) = pw;
        }
      }
      asm volatile("s_waitcnt lgkmcnt(0)" ::: "memory");

      // O^T += V^T @ P^T ; denominator += ones @ P^T (matrix-pipe row-sum)
      __builtin_amdgcn_s_setprio(1);
#pragma unroll
      for (int ks = 0; ks < 2; ++ks) {
        bf16x8 vf[4], pf[2];
#pragma unroll
        for (int n2 = 0; n2 < 4; ++n2)
          vf[n2] = *reinterpret_cast<const bf16x8*>(
              &Vs[(n2 * 16 + l15) * 64 + (((ks * 4 + g) ^ sw) * 8)]);
#pragma unroll
        for (int m = 0; m < 2; ++m)
          pf[m] = *reinterpret_cast<const bf16x8*>(
              &Pw[(m * 16 + l15) * 64 + (((ks * 4 + g) ^ sw) * 8)]);
#pragma unroll
        for (int m = 0; m < 2; ++m) {
#pragma unroll
          for (int n2 = 0; n2 < 4; ++n2)
            o[m][n2] = __builtin_amdgcn_mfma_f32_16x16x32_bf16(vf[n2], pf[m], o[m][n2], 0, 0, 0);
          po[m] = __builtin_amdgcn_mfma_f32_16x16x32_bf16(ones, pf[m], po[m], 0, 0, 0);
        }
      }
      __builtin_amdgcn_s_setprio(0);
    }
    asm volatile("" ::: "memory");
    __builtin_amdgcn_s_barrier();
    // V(t+1) staged only after ALL waves passed the barrier (done reading Vs)
    if (haveNext) stage_v(Vt, Vs, h, st + 1, wid, lane);
    cur ^= 1;
  }

  if (nch == 1) {
#pragma unroll
    for (int m = 0; m < 2; ++m) {
      float inv = 1.0f / po[m][0];
      int qg = qw + m * 16 + l15;
#pragma unroll
      for (int n2 = 0; n2 < 4; ++n2) {
        uint2 yk;
        yk.x = cvtpk(o[m][n2][0] * inv, o[m][n2][1] * inv);
        yk.y = cvtpk(o[m][n2][2] * inv, o[m][n2][3] * inv);
        *reinterpret_cast<uint2*>(&Y[(size_t)qg * C_DIM + h * 64 + n2 * 16 + g * 4]) = yk;
      }
    }
  } else {
    const int set = h * 96 + part_off(qb) + ck;
    unsigned short* po_ = part_ptr(partA, partB, set);
#pragma unroll
    for (int m = 0; m < 2; ++m) {
      int qL = wid * 32 + m * 16 + l15;
#pragma unroll
      for (int n2 = 0; n2 < 4; ++n2) {
        uint2 pk;
        pk.x = cvtpk(o[m][n2][0], o[m][n2][1]);
        pk.y = cvtpk(o[m][n2][2], o[m][n2][3]);
        *reinterpret_cast<uint2*>(&po_[qL * 64 + n2 * 16 + g * 4]) = pk;
      }
      if (g == 0) {
        ml[(size_t)set * 256 + qL * 2] = mrow[m];
        ml[(size_t)set * 256 + qL * 2 + 1] = po[m][0];
      }
    }
  }
}

// ---------------- combine partials (exp2 domain) ----------------
// grid (26, NH): qb = 6 + bx
__global__ __launch_bounds__(256)
void attn_combine(char* __restrict__ partA, char* __restrict__ partB,
                  const float* __restrict__ ml, unsigned short* __restrict__ Y) {
  const int qb = 6 + blockIdx.x;
  const int h = blockIdx.y;
  const int nch = nchunks(qb);
  const int set0 = h * 96 + part_off(qb);
  const int t = threadIdx.x;
  const int r = t >> 1, dh = (t & 1) * 32;

  float mi[6], li[6];
  float M = -1e30f;
  for (int i = 0; i < nch; ++i) {
    mi[i] = ml[(size_t)(set0 + i) * 256 + r * 2];
    li[i] = ml[(size_t)(set0 + i) * 256 + r * 2 + 1];
    M = fmaxf(M, mi[i]);
  }
  float L = 0.f;
  float O[32];
#pragma unroll
  for (int d = 0; d < 32; ++d) O[d] = 0.f;
  for (int i = 0; i < nch; ++i) {
    float w = E2(mi[i] - M);
    L += li[i] * w;
    const unsigned short* po = part_ptr(partA, partB, set0 + i) + r * 64 + dh;
#pragma unroll
    for (int d4 = 0; d4 < 32; d4 += 4) {
      ushort4 v = *reinterpret_cast<const ushort4*>(po + d4);
      O[d4 + 0] += bf2f(v.x) * w;
      O[d4 + 1] += bf2f(v.y) * w;
      O[d4 + 2] += bf2f(v.z) * w;
      O[d4 + 3] += bf2f(v.w) * w;
    }
  }
  float inv = 1.0f / L;
  unsigned short* yp = Y + (size_t)(qb * 128 + r) * C_DIM + h * 64 + dh;
#pragma unroll
  for (int d4 = 0; d4 < 32; d4 += 4) {
    uint2 yk;
    yk.x = cvtpk(O[d4 + 0] * inv, O[d4 + 1] * inv);
    yk.y = cvtpk(O[d4 + 2] * inv, O[d4 + 3] * inv);
    *reinterpret_cast<uint2*>(yp + d4) = yk;
  }
}

// ---------------- launcher ----------------
extern "C" void kernel_launch(void* const* d_in, const int* in_sizes, int n_in,
                              void* d_out, int out_size, void* d_ws, size_t ws_size,
                              hipStream_t stream) {
  const float* x = (const float*)d_in[0];       // [4096][768]
  const float* w_attn = (const float*)d_in[1];  // [768][2304]
  const float* w_proj = (const float*)d_in[2];  // [768][768]
  float* out = (float*)d_out;                   // [4096][768] f32

  char* ws = (char*)d_ws;
  unsigned short* Xb   = (unsigned short*)(ws + 0);          // 6291456 B (dead after QKV -> part spill B)
  unsigned short* WaT  = (unsigned short*)(ws + 6291456);    // 3538944 B (dead after QKV -> ml)
  unsigned short* WpT  = (unsigned short*)(ws + 9830400);    // 1179648 B [768][768]
  unsigned short* Qb   = (unsigned short*)(ws + 11010048);   // 6291456 B [T][768]
  unsigned short* Kb   = (unsigned short*)(ws + 17301504);   // 6291456 B [T][768]
  unsigned short* Vt   = (unsigned short*)(ws + 23592960);   // 6291456 B [768][T]
  unsigned short* Yb   = (unsigned short*)(ws + 29884416);   // 6291456 B [T][768]

  char* partA = (char*)d_out;            // free during attention; overwritten by proj GEMM
  char* partB = (char*)ws;               // Xb region, dead after QKV GEMM
  float* mlp  = (float*)(ws + 6291456);  // WaT region, dead after QKV GEMM

  prep<<<5376, 256, 0, stream>>>(x, Xb, w_attn, WaT, w_proj, WpT);

  gemm_bt<0, 64, 64><<<(T_SEQ / 64) * (2304 / 64), 256, 0, stream>>>(
      Xb, WaT, (void*)Qb, Kb, Vt, T_SEQ, 2304, C_DIM);

  attn_fwd<<<dim3(NH, 102), 256, 0, stream>>>(Qb, Kb, Vt, Yb, partA, partB, mlp);
  attn_combine<<<dim3(26, NH), 256, 0, stream>>>(partA, partB, mlp, Yb);

  gemm_bt<1, 64, 64><<<(T_SEQ / 64) * (C_DIM / 64), 256, 0, stream>>>(
      Yb, WpT, (void*)out, nullptr, nullptr, T_SEQ, C_DIM, C_DIM);
}

// Round 18
// 120.024 us; speedup vs baseline: 1.1728x; 1.0015x over previous
//
#include <hip/hip_runtime.h>

// Causal self-attention: B=1, T=4096, C=768, H=12, hd=64
// f32 in/out, bf16 MFMA compute internally. Flash-decoding s-split.
// R18: REVERT to R16 (120.2us verified). R17's single-barrier rotate raced:
// vmcnt is PER-WAVE, so the barrier must come AFTER each wave's vmcnt for
// cross-wave staged segments to be visible -- two barriers are the minimum
// for a 2-buffer pipeline (3 buffers would be needed for single-barrier).

typedef short bf16x8 __attribute__((ext_vector_type(8)));
typedef float f32x4 __attribute__((ext_vector_type(4)));

#define T_SEQ 4096
#define C_DIM 768
#define NH 12
#define HD 64

__device__ __forceinline__ unsigned short f2bf(float f) {
  union { float f; unsigned u; } v; v.f = f;
  unsigned r = v.u + 0x7FFFu + ((v.u >> 16) & 1u);
  return (unsigned short)(r >> 16);
}
__device__ __forceinline__ float bf2f(unsigned short u) {
  union { unsigned u; float f; } v; v.u = ((unsigned)u) << 16;
  return v.f;
}
__device__ __forceinline__ unsigned cvtpk(float a, float b) {
  unsigned r;
  asm("v_cvt_pk_bf16_f32 %0, %1, %2" : "=v"(r) : "v"(a), "v"(b));
  return r;
}
#define E2(x) __builtin_amdgcn_exp2f(x)

#define GLD16(g, l) __builtin_amdgcn_global_load_lds( \
    (const __attribute__((address_space(1))) void*)(g), \
    (__attribute__((address_space(3))) void*)(l), 16, 0, 0)

// ---------------- fused prep: f32->bf16 conv + 2 weight transposes ----------------
__device__ __forceinline__ void tr_body(const float* __restrict__ in,
                                        unsigned short* __restrict__ out,
                                        int R, int Cc, int bx, int by,
                                        float (*tile)[33]) {
  int tx = threadIdx.x & 31, ty = threadIdx.x >> 5;
#pragma unroll
  for (int i = 0; i < 32; i += 8)
    tile[ty + i][tx] = in[(size_t)(by * 32 + ty + i) * Cc + bx * 32 + tx];
  __syncthreads();
#pragma unroll
  for (int i = 0; i < 32; i += 8)
    out[(size_t)(bx * 32 + ty + i) * R + by * 32 + tx] = f2bf(tile[tx][ty + i]);
}

__global__ void prep(const float* __restrict__ x, unsigned short* __restrict__ Xb,
                     const float* __restrict__ w_attn, unsigned short* __restrict__ WaT,
                     const float* __restrict__ w_proj, unsigned short* __restrict__ WpT) {
  __shared__ float tile[32][33];
  const int bid = blockIdx.x;
  if (bid < 3072) {                       // conv x: 4096x768 f32 -> bf16
    int i = (bid * 256 + threadIdx.x) * 4;
    float4 v = *reinterpret_cast<const float4*>(x + i);
    ushort4 o;
    o.x = f2bf(v.x); o.y = f2bf(v.y); o.z = f2bf(v.z); o.w = f2bf(v.w);
    *reinterpret_cast<ushort4*>(Xb + i) = o;
  } else if (bid < 3072 + 1728) {         // w_attn^T: 768x2304 -> [2304][768]
    int b = bid - 3072;
    tr_body(w_attn, WaT, 768, 2304, b % 72, b / 72, tile);
  } else {                                // w_proj^T: 768x768 -> [768][768]
    int b = bid - 4800;
    tr_body(w_proj, WpT, 768, 768, b % 24, b / 24, tile);
  }
}

// ---------------- BT-GEMM: A[M][K] bf16 @ Bt[N][K] bf16 ----------------
// Double-buffered LDS, counted vmcnt (loads stay in flight across barriers),
// 1-D grid with bijective XCD swizzle. Two barriers per iter (vmcnt is
// per-wave: barrier must follow vmcnt for cross-wave segment visibility).
template <int MODE, int BM, int BN>
__global__ __launch_bounds__(256, 4)
void gemm_bt(const unsigned short* __restrict__ A,
             const unsigned short* __restrict__ Bt,
             void* __restrict__ out0,
             unsigned short* __restrict__ Kout,
             unsigned short* __restrict__ Vt,
             int M, int N, int K) {
  __shared__ __align__(16) unsigned short smem[2 * (BM + BN) * 64];
  constexpr int AM = BM / 32, AN = BN / 32;   // acc tile counts per wave
  const int nbn = N / BN;
  const int nwg = (M / BM) * nbn;
  const int cpx = nwg >> 3;               // nwg % 8 == 0 (2304, 768)
  const int swz = ((int)blockIdx.x & 7) * cpx + ((int)blockIdx.x >> 3);
  const int bm = swz / nbn, bn = swz % nbn;
  const int tid = threadIdx.x;
  const int wid = tid >> 6, lane = tid & 63;
  const int wr = wid >> 1, wc = wid & 1;
  const int lr = lane & 15;
  const int lk8 = (lane >> 4) * 8;
  const int rsub = lane >> 3, csub = (lane & 7) * 8;

  auto Abuf = [&](int b) { return smem + b * BM * 64; };
  auto Bbuf = [&](int b) { return smem + 2 * BM * 64 + b * BN * 64; };

  f32x4 acc[AM][AN] = {};
  const int nk = K / 64;

  auto STAGE = [&](int kt, int buf) {
    const unsigned short* gA = A + (size_t)(bm * BM) * K + kt * 64;
    const unsigned short* gB = Bt + (size_t)(bn * BN) * K + kt * 64;
#pragma unroll
    for (int c = 0; c < BM / 32; ++c) {
      int seg = wid * (BM / 32) + c;
      int row = seg * 8 + rsub;
      GLD16(gA + (size_t)row * K + csub, (char*)Abuf(buf) + seg * 1024);
    }
#pragma unroll
    for (int c = 0; c < BN / 32; ++c) {
      int seg = wid * (BN / 32) + c;
      int row = seg * 8 + rsub;
      GLD16(gB + (size_t)row * K + csub, (char*)Bbuf(buf) + seg * 1024);
    }
  };

  STAGE(0, 0);
  int cur = 0;
  for (int kt = 0; kt < nk; ++kt) {
    if (kt + 1 < nk) {
      STAGE(kt + 1, cur ^ 1);
      constexpr int LOADS = BM / 32 + BN / 32;  // per-wave loads per stage
      if constexpr (LOADS == 4)
        asm volatile("s_waitcnt vmcnt(4)" ::: "memory");
      else if constexpr (LOADS == 6)
        asm volatile("s_waitcnt vmcnt(6)" ::: "memory");
      else
        asm volatile("s_waitcnt vmcnt(0)" ::: "memory");
    } else {
      asm volatile("s_waitcnt vmcnt(0)" ::: "memory");
    }
    __builtin_amdgcn_s_barrier();

    const unsigned short* As = Abuf(cur);
    const unsigned short* Bs = Bbuf(cur);
#pragma unroll
    for (int kk = 0; kk < 2; ++kk) {
      bf16x8 a[AM], b[AN];
      int lk = kk * 32 + lk8;
#pragma unroll
      for (int m = 0; m < AM; ++m)
        a[m] = *reinterpret_cast<const bf16x8*>(&As[(wr * (BM / 2) + m * 16 + lr) * 64 + lk]);
#pragma unroll
      for (int n = 0; n < AN; ++n)
        b[n] = *reinterpret_cast<const bf16x8*>(&Bs[(wc * (BN / 2) + n * 16 + lr) * 64 + lk]);
#pragma unroll
      for (int m = 0; m < AM; ++m)
#pragma unroll
        for (int n = 0; n < AN; ++n)
          acc[m][n] = __builtin_amdgcn_mfma_f32_16x16x32_bf16(a[m], b[n], acc[m][n], 0, 0, 0);
    }
    asm volatile("" ::: "memory");
    __builtin_amdgcn_s_barrier();  // all waves done reading buf[cur] before re-stage
    cur ^= 1;
  }

  const int row0 = bm * BM + wr * (BM / 2);
  const int col0 = bn * BN + wc * (BN / 2);
  const int g = lane >> 4;

  if constexpr (MODE == 0) {
    if (bn * BN >= 1536) {
      // V block: coalesced V^T store via padded LDS transpose.
      // Overlay the (now dead) staging buffers.
      __syncthreads();
      unsigned short (*Vst)[72] = reinterpret_cast<unsigned short (*)[72]>(smem);
      const int dl0 = wc * (BN / 2);
      const int tl0 = wr * (BM / 2);
#pragma unroll
      for (int m = 0; m < AM; ++m)
#pragma unroll
        for (int n = 0; n < AN; ++n) {
          uint2 pk;
          pk.x = cvtpk(acc[m][n][0], acc[m][n][1]);
          pk.y = cvtpk(acc[m][n][2], acc[m][n][3]);
          *reinterpret_cast<uint2*>(&Vst[dl0 + n * 16 + lr][tl0 + m * 16 + g * 4]) = pk;
        }
      __syncthreads();
      const int dl = tid >> 2;
      const int tb = (tid & 3) * 16;
      uint4 a0 = *reinterpret_cast<const uint4*>(&Vst[dl][tb]);
      uint4 a1 = *reinterpret_cast<const uint4*>(&Vst[dl][tb + 8]);
      unsigned short* dst = Vt + (size_t)(bn * BN - 1536 + dl) * M + bm * BM + tb;
      *reinterpret_cast<uint4*>(dst) = a0;
      *reinterpret_cast<uint4*>(dst + 8) = a1;
      return;
    }
  }

#pragma unroll
  for (int m = 0; m < AM; ++m)
#pragma unroll
    for (int n = 0; n < AN; ++n)
#pragma unroll
      for (int j = 0; j < 4; ++j) {
        int r = row0 + m * 16 + g * 4 + j;
        int c = col0 + n * 16 + lr;
        float v = acc[m][n][j];
        if (MODE == 0) {
          if (c < 768)  // Q pre-scaled by (1/8)*log2(e) for exp2-domain softmax
            ((unsigned short*)out0)[(size_t)r * 768 + c] = f2bf(v * 0.180336884f);
          else
            Kout[(size_t)r * 768 + (c - 768)] = f2bf(v);
        } else {
          ((float*)out0)[(size_t)r * N + c] = v;
        }
      }
}

// ---------------- attention helpers ----------------
__device__ __forceinline__ void stage_k(const unsigned short* __restrict__ Kb,
                                        unsigned short* Kbuf,
                                        int h, int st, int wid, int lane) {
  const int cg = lane & 7, rsub = (lane >> 3) & 7;
  const unsigned short* gK = Kb + (size_t)(st * 64) * C_DIM + h * 64;
#pragma unroll
  for (int c = 0; c < 2; ++c) {
    int seg = wid * 2 + c;
    int row = seg * 8 + rsub;
    GLD16(gK + (size_t)row * C_DIM + (cg ^ rsub) * 8, (char*)Kbuf + seg * 1024);
  }
}
__device__ __forceinline__ void stage_v(const unsigned short* __restrict__ Vt,
                                        unsigned short* Vbuf,
                                        int h, int st, int wid, int lane) {
  const int cg = lane & 7, rsub = (lane >> 3) & 7;
  const unsigned short* gV = Vt + (size_t)(h * 64) * T_SEQ + st * 64;
#pragma unroll
  for (int c = 0; c < 2; ++c) {
    int seg = wid * 2 + c;
    int row = seg * 8 + rsub;
    GLD16(gV + (size_t)row * T_SEQ + (cg ^ rsub) * 8, (char*)Vbuf + seg * 1024);
  }
}

// chunk size 12 tiles; nst_total = 2qb+2; nch = ceil((2qb+2)/12)
__device__ __forceinline__ int nchunks(int q) { return (2 * q + 13) / 12; }
// partial sets for qb>=6 (nch>=2): 96 sets/head
__device__ __forceinline__ int part_off(int qb) {
  if (qb < 12) return (qb - 6) * 2;
  if (qb < 18) return 12 + (qb - 12) * 3;
  if (qb < 24) return 30 + (qb - 18) * 4;
  if (qb < 30) return 54 + (qb - 24) * 5;
  return 84 + (qb - 30) * 6;
}
// 1152 sets x 16KB: 768 in d_out, 384 in Xb region
__device__ __forceinline__ unsigned short* part_ptr(char* pA, char* pB, int set) {
  return (set < 768) ? (unsigned short*)(pA + (size_t)set * 16384)
                     : (unsigned short*)(pB + (size_t)(set - 768) * 16384);
}

// ---------------- flash attention (causal, swapped QK^T, s-chunked) ----------------
// grid = (NH, 102): x = head (fastest dispatch dim) -> LPT across heads.
// K double-buffered, V single-buffered (staged after end barrier): LDS 40KB.
__global__ __launch_bounds__(256, 3)
void attn_fwd(const unsigned short* __restrict__ Qb,
              const unsigned short* __restrict__ Kb,
              const unsigned short* __restrict__ Vt,
              unsigned short* __restrict__ Y,
              char* __restrict__ partA, char* __restrict__ partB,
              float* __restrict__ ml) {
  __shared__ __align__(16) unsigned short Ks[2][64 * 64];
  __shared__ __align__(16) unsigned short Vs[64 * 64];  // [d][s], single buffer
  __shared__ __align__(16) unsigned short Ps[4][32 * 64];

  const int h = blockIdx.x;
  int qb = 0, ck = 0;
  {
    int idx = blockIdx.y;
    for (int q = 31; q >= 0; --q) {
      int nc = nchunks(q);
      if (idx < nc) { qb = q; ck = idx; break; }
      idx -= nc;
    }
  }
  const int nch = nchunks(qb);
  const int q0 = qb * 128;
  const int nst_total = 2 * qb + 2;
  const int st0 = ck * 12;
  const int st1 = (st0 + 12 < nst_total) ? st0 + 12 : nst_total;

  const int tid = threadIdx.x;
  const int wid = tid >> 6, lane = tid & 63;
  const int l15 = lane & 15, g = lane >> 4;
  const int sw = l15 & 7;
  const int qw = q0 + wid * 32;

  bf16x8 qf[2][2];
#pragma unroll
  for (int m = 0; m < 2; ++m)
#pragma unroll
    for (int kk = 0; kk < 2; ++kk)
      qf[m][kk] = *reinterpret_cast<const bf16x8*>(
          &Qb[(size_t)(qw + m * 16 + l15) * C_DIM + h * 64 + kk * 32 + g * 8]);

  // all-ones bf16 A-fragment for the denominator MFMA (bf16 1.0 = 0x3F80)
  bf16x8 ones;
#pragma unroll
  for (int e = 0; e < 8; ++e) ones[e] = (short)0x3F80;

  f32x4 o[2][4] = {};  // O^T fragments: row=d, col=q
  f32x4 po[2] = {};    // denominator accumulator: every reg = sum_s P[q][s]
  float mrow[2] = {-1e30f, -1e30f};

  stage_k(Kb, Ks[0], h, st0, wid, lane);
  stage_v(Vt, Vs, h, st0, wid, lane);
  int cur = 0;

  for (int st = st0; st < st1; ++st) {
    const bool haveNext = (st + 1 < st1);
    if (haveNext) {
      stage_k(Kb, Ks[cur ^ 1], h, st + 1, wid, lane);
      // queue: [K(t):2, V(t):2, K(t+1):2] -> wait K(t),V(t); K(t+1) in flight
      asm volatile("s_waitcnt vmcnt(2)" ::: "memory");
    } else {
      asm volatile("s_waitcnt vmcnt(0)" ::: "memory");
    }
    __builtin_amdgcn_s_barrier();

    const bool active = (st * 64) <= (qw + 31);
    if (active) {
      const unsigned short* K_ = Ks[cur];

      // S^T = K @ Q^T  (S in log2 domain: Q pre-scaled by 0.125*log2e)
      f32x4 sT[2][4] = {};
      __builtin_amdgcn_s_setprio(1);
#pragma unroll
      for (int kk = 0; kk < 2; ++kk) {
        bf16x8 kf[4];
#pragma unroll
        for (int n = 0; n < 4; ++n)
          kf[n] = *reinterpret_cast<const bf16x8*>(
              &K_[(n * 16 + l15) * 64 + (((kk * 4 + g) ^ sw) * 8)]);
#pragma unroll
        for (int m = 0; m < 2; ++m)
#pragma unroll
          for (int n = 0; n < 4; ++n)
            sT[m][n] = __builtin_amdgcn_mfma_f32_16x16x32_bf16(kf[n], qf[m][kk], sT[m][n], 0, 0, 0);
      }
      __builtin_amdgcn_s_setprio(0);

      unsigned short* Pw = Ps[wid];
#pragma unroll
      for (int m = 0; m < 2; ++m) {
        if (!(st * 64 + 63 <= qw + m * 16)) {
          // diagonal tile: apply causal mask (rare, wave-uniform branch)
          const int bound = (qw + m * 16 + l15) - st * 64;
#pragma unroll
          for (int n = 0; n < 4; ++n)
#pragma unroll
            for (int jj = 0; jj < 4; ++jj) {
              int sl = n * 16 + g * 4 + jj;
              if (sl > bound) sT[m][n][jj] = -1e30f;
            }
        }
        // tree max
        float vm[4];
#pragma unroll
        for (int n = 0; n < 4; ++n)
          vm[n] = fmaxf(fmaxf(sT[m][n][0], sT[m][n][1]), fmaxf(sT[m][n][2], sT[m][n][3]));
        float vmax = fmaxf(fmaxf(vm[0], vm[1]), fmaxf(vm[2], vm[3]));
        vmax = fmaxf(vmax, __shfl_xor(vmax, 16, 64));
        vmax = fmaxf(vmax, __shfl_xor(vmax, 32, 64));
        // defer-rescale (T13): keep old max while growth <= 8 (P bounded by 2^8)
        const bool defer = (__all(vmax <= mrow[m] + 8.0f) != 0);
        const float mnew = defer ? mrow[m] : fmaxf(mrow[m], vmax);
#pragma unroll
        for (int n = 0; n < 4; ++n)
#pragma unroll
          for (int jj = 0; jj < 4; ++jj)
            sT[m][n][jj] = E2(sT[m][n][jj] - mnew);
        if (!defer) {
          float alpha = E2(mrow[m] - mnew);
          mrow[m] = mnew;
#pragma unroll
          for (int n2 = 0; n2 < 4; ++n2) o[m][n2] *= alpha;
          po[m] *= alpha;
        }
#pragma unroll
        for (int n = 0; n < 4; ++n) {
          uint2 pw;
          pw.x = cvtpk(sT[m][n][0], sT[m][n][1]);
          pw.y = cvtpk(sT[m][n][2], sT[m][n][3]);
          *reinterpret_cast<uint2*>(
              &Pw[(m * 16 + l15) * 64 + (((n * 2 + (g >> 1)) ^ sw) * 8) + (g & 1) * 4]) = pw;
        }
      }
      asm volatile("s_waitcnt lgkmcnt(0)" ::: "memory");

      // O^T += V^T @ P^T ; denominator += ones @ P^T (matrix-pipe row-sum)
      __builtin_amdgcn_s_setprio(1);
#pragma unroll
      for (int ks = 0; ks < 2; ++ks) {
        bf16x8 vf[4], pf[2];
#pragma unroll
        for (int n2 = 0; n2 < 4; ++n2)
          vf[n2] = *reinterpret_cast<const bf16x8*>(
              &Vs[(n2 * 16 + l15) * 64 + (((ks * 4 + g) ^ sw) * 8)]);
#pragma unroll
        for (int m = 0; m < 2; ++m)
          pf[m] = *reinterpret_cast<const bf16x8*>(
              &Pw[(m * 16 + l15) * 64 + (((ks * 4 + g) ^ sw) * 8)]);
#pragma unroll
        for (int m = 0; m < 2; ++m) {
#pragma unroll
          for (int n2 = 0; n2 < 4; ++n2)
            o[m][n2] = __builtin_amdgcn_mfma_f32_16x16x32_bf16(vf[n2], pf[m], o[m][n2], 0, 0, 0);
          po[m] = __builtin_amdgcn_mfma_f32_16x16x32_bf16(ones, pf[m], po[m], 0, 0, 0);
        }
      }
      __builtin_amdgcn_s_setprio(0);
    }
    asm volatile("" ::: "memory");
    __builtin_amdgcn_s_barrier();
    // V(t+1) staged only after ALL waves passed the barrier (done reading Vs)
    if (haveNext) stage_v(Vt, Vs, h, st + 1, wid, lane);
    cur ^= 1;
  }

  if (nch == 1) {
#pragma unroll
    for (int m = 0; m < 2; ++m) {
      float inv = 1.0f / po[m][0];
      int qg = qw + m * 16 + l15;
#pragma unroll
      for (int n2 = 0; n2 < 4; ++n2) {
        uint2 yk;
        yk.x = cvtpk(o[m][n2][0] * inv, o[m][n2][1] * inv);
        yk.y = cvtpk(o[m][n2][2] * inv, o[m][n2][3] * inv);
        *reinterpret_cast<uint2*>(&Y[(size_t)qg * C_DIM + h * 64 + n2 * 16 + g * 4]) = yk;
      }
    }
  } else {
    const int set = h * 96 + part_off(qb) + ck;
    unsigned short* po_ = part_ptr(partA, partB, set);
#pragma unroll
    for (int m = 0; m < 2; ++m) {
      int qL = wid * 32 + m * 16 + l15;
#pragma unroll
      for (int n2 = 0; n2 < 4; ++n2) {
        uint2 pk;
        pk.x = cvtpk(o[m][n2][0], o[m][n2][1]);
        pk.y = cvtpk(o[m][n2][2], o[m][n2][3]);
        *reinterpret_cast<uint2*>(&po_[qL * 64 + n2 * 16 + g * 4]) = pk;
      }
      if (g == 0) {
        ml[(size_t)set * 256 + qL * 2] = mrow[m];
        ml[(size_t)set * 256 + qL * 2 + 1] = po[m][0];
      }
    }
  }
}

// ---------------- combine partials (exp2 domain) ----------------
// grid (26, NH): qb = 6 + bx
__global__ __launch_bounds__(256)
void attn_combine(char* __restrict__ partA, char* __restrict__ partB,
                  const float* __restrict__ ml, unsigned short* __restrict__ Y) {
  const int qb = 6 + blockIdx.x;
  const int h = blockIdx.y;
  const int nch = nchunks(qb);
  const int set0 = h * 96 + part_off(qb);
  const int t = threadIdx.x;
  const int r = t >> 1, dh = (t & 1) * 32;

  float mi[6], li[6];
  float M = -1e30f;
  for (int i = 0; i < nch; ++i) {
    mi[i] = ml[(size_t)(set0 + i) * 256 + r * 2];
    li[i] = ml[(size_t)(set0 + i) * 256 + r * 2 + 1];
    M = fmaxf(M, mi[i]);
  }
  float L = 0.f;
  float O[32];
#pragma unroll
  for (int d = 0; d < 32; ++d) O[d] = 0.f;
  for (int i = 0; i < nch; ++i) {
    float w = E2(mi[i] - M);
    L += li[i] * w;
    const unsigned short* po = part_ptr(partA, partB, set0 + i) + r * 64 + dh;
#pragma unroll
    for (int d4 = 0; d4 < 32; d4 += 4) {
      ushort4 v = *reinterpret_cast<const ushort4*>(po + d4);
      O[d4 + 0] += bf2f(v.x) * w;
      O[d4 + 1] += bf2f(v.y) * w;
      O[d4 + 2] += bf2f(v.z) * w;
      O[d4 + 3] += bf2f(v.w) * w;
    }
  }
  float inv = 1.0f / L;
  unsigned short* yp = Y + (size_t)(qb * 128 + r) * C_DIM + h * 64 + dh;
#pragma unroll
  for (int d4 = 0; d4 < 32; d4 += 4) {
    uint2 yk;
    yk.x = cvtpk(O[d4 + 0] * inv, O[d4 + 1] * inv);
    yk.y = cvtpk(O[d4 + 2] * inv, O[d4 + 3] * inv);
    *reinterpret_cast<uint2*>(yp + d4) = yk;
  }
}

// ---------------- launcher ----------------
extern "C" void kernel_launch(void* const* d_in, const int* in_sizes, int n_in,
                              void* d_out, int out_size, void* d_ws, size_t ws_size,
                              hipStream_t stream) {
  const float* x = (const float*)d_in[0];       // [4096][768]
  const float* w_attn = (const float*)d_in[1];  // [768][2304]
  const float* w_proj = (const float*)d_in[2];  // [768][768]
  float* out = (float*)d_out;                   // [4096][768] f32

  char* ws = (char*)d_ws;
  unsigned short* Xb   = (unsigned short*)(ws + 0);          // 6291456 B (dead after QKV -> part spill B)
  unsigned short* WaT  = (unsigned short*)(ws + 6291456);    // 3538944 B (dead after QKV -> ml)
  unsigned short* WpT  = (unsigned short*)(ws + 9830400);    // 1179648 B [768][768]
  unsigned short* Qb   = (unsigned short*)(ws + 11010048);   // 6291456 B [T][768]
  unsigned short* Kb   = (unsigned short*)(ws + 17301504);   // 6291456 B [T][768]
  unsigned short* Vt   = (unsigned short*)(ws + 23592960);   // 6291456 B [768][T]
  unsigned short* Yb   = (unsigned short*)(ws + 29884416);   // 6291456 B [T][768]

  char* partA = (char*)d_out;            // free during attention; overwritten by proj GEMM
  char* partB = (char*)ws;               // Xb region, dead after QKV GEMM
  float* mlp  = (float*)(ws + 6291456);  // WaT region, dead after QKV GEMM

  prep<<<5376, 256, 0, stream>>>(x, Xb, w_attn, WaT, w_proj, WpT);

  gemm_bt<0, 64, 64><<<(T_SEQ / 64) * (2304 / 64), 256, 0, stream>>>(
      Xb, WaT, (void*)Qb, Kb, Vt, T_SEQ, 2304, C_DIM);

  attn_fwd<<<dim3(NH, 102), 256, 0, stream>>>(Qb, Kb, Vt, Yb, partA, partB, mlp);
  attn_combine<<<dim3(26, NH), 256, 0, stream>>>(partA, partB, mlp, Yb);

  gemm_bt<1, 64, 64><<<(T_SEQ / 64) * (C_DIM / 64), 256, 0, stream>>>(
      Yb, WpT, (void*)out, nullptr, nullptr, T_SEQ, C_DIM, C_DIM);
}